// Round 4
// baseline (527.953 us; speedup 1.0000x reference)
//
#include <hip/hip_runtime.h>
#include <hip/hip_bf16.h>
#include <math.h>

typedef unsigned short u16;
typedef unsigned int   u32;

#define CC 512
#define NN 196
#define NP 256
#define TT 4
#define BB 32
#define TBB 128
#define NHH 8
#define HD 64

typedef __attribute__((ext_vector_type(8))) short bf16x8;
typedef __attribute__((ext_vector_type(4))) float f32x4;

#define TSTRIDE   ((size_t)BB * NP * CC)          // 4,194,304 elems per t-slice

__device__ __forceinline__ u16 f2bf(float f) {
    __hip_bfloat16 h = __float2bfloat16(f);
    return *(u16*)&h;
}
__device__ __forceinline__ float bf2f(u16 u) {
    u32 ui = ((u32)u) << 16;
    return __uint_as_float(ui);
}
__device__ __forceinline__ u32 pk2(u16 a, u16 b) { return (u32)a | ((u32)b << 16); }

// async 16B/lane global->LDS; lds base must be wave-uniform
__device__ __forceinline__ void gld16(const void* g, void* l) {
    __builtin_amdgcn_global_load_lds(
        (const __attribute__((address_space(1))) void*)g,
        (__attribute__((address_space(3))) void*)l, 16, 0, 0);
}

// ---------------- prep: split fp32 weights into 3 exact bf16 planes ----------------
__global__ __launch_bounds__(256) void k_prep_w(const float* __restrict__ qw, const float* __restrict__ kw,
                                                const float* __restrict__ vw, const float* __restrict__ pw,
                                                u16* __restrict__ W3) {
    size_t idx = (size_t)blockIdx.x * 256 + threadIdx.x;   // 4 * 262144
    int g = (int)(idx >> 18);
    size_t rem = idx & 262143;
    const float* Ws = (g == 0) ? qw : (g == 1) ? kw : (g == 2) ? vw : pw;
    float w  = Ws[rem];
    u16 u0 = f2bf(w);      float b0 = bf2f(u0);
    float r1 = w - b0;
    u16 u1 = f2bf(r1);     float b1 = bf2f(u1);
    float r2 = r1 - b1;
    u16 u2 = f2bf(r2);
    size_t base = (size_t)g * 786432 + rem;
    W3[base] = u0; W3[base + 262144] = u1; W3[base + 524288] = u2;
}

// all 4 BN param groups in one launch: grid 8 x 256 = 2048 = 4 groups x 512
__global__ __launch_bounds__(256) void k_prep_bn4(
    const float* __restrict__ cb0, const float* __restrict__ bg0, const float* __restrict__ bb0,
    const float* __restrict__ bm0, const float* __restrict__ bv0,
    const float* __restrict__ cb1, const float* __restrict__ bg1, const float* __restrict__ bb1,
    const float* __restrict__ bm1, const float* __restrict__ bv1,
    const float* __restrict__ cb2, const float* __restrict__ bg2, const float* __restrict__ bb2,
    const float* __restrict__ bm2, const float* __restrict__ bv2,
    const float* __restrict__ cb3, const float* __restrict__ bg3, const float* __restrict__ bb3,
    const float* __restrict__ bm3, const float* __restrict__ bv3,
    float* __restrict__ SS, float* __restrict__ SH) {
    int idx = blockIdx.x * 256 + threadIdx.x;
    int g = idx >> 9, o = idx & 511;
    const float* cb = g == 0 ? cb0 : g == 1 ? cb1 : g == 2 ? cb2 : cb3;
    const float* bg = g == 0 ? bg0 : g == 1 ? bg1 : g == 2 ? bg2 : bg3;
    const float* bb = g == 0 ? bb0 : g == 1 ? bb1 : g == 2 ? bb2 : bb3;
    const float* bm = g == 0 ? bm0 : g == 1 ? bm1 : g == 2 ? bm2 : bm3;
    const float* bv = g == 0 ? bv0 : g == 1 ? bv1 : g == 2 ? bv2 : bv3;
    float inv = bg[o] / sqrtf(bv[o] + 1e-5f);
    SS[g * 512 + o] = inv;
    SH[g * 512 + o] = (cb[o] - bm[o]) * inv + bb[o];
}

// ---------------- head LIF + transpose: x[t][b][C][196] -> XS[tb][n(256)][C] bf16 spikes ----------------
__global__ __launch_bounds__(256) void k_head_lif(const float* __restrict__ x, u16* __restrict__ XS) {
    __shared__ float T[64][65];
    const int tid = threadIdx.x;
    const int n0 = blockIdx.x * 64;       // 0..3 * 64
    const int b  = blockIdx.y;            // 0..31
    const int ch = blockIdx.z;            // 0..1
    const int n_l = tid & 63;
    const int c_r0 = tid >> 6;            // 0..3
    const int n_r = tid >> 2;             // 0..63
    const int cq  = (tid & 3) * 16;

    for (int cc = 0; cc < 4; ++cc) {
        const int c_base = ch * 256 + cc * 64;
        float v[16];
        #pragma unroll
        for (int j = 0; j < 16; ++j) v[j] = 0.f;
        for (int t = 0; t < TT; ++t) {
            const size_t xb = ((size_t)(t * BB + b) * CC + c_base) * NN;
            float s[16];
            #pragma unroll
            for (int j = 0; j < 16; ++j) {
                int c_l = c_r0 + 4 * j;
                float xv = (n0 + n_l < NN) ? x[xb + (size_t)c_l * NN + n0 + n_l] : 0.f;
                float h = v[j] + (xv - v[j]) * 0.5f;
                s[j] = (h >= 1.f) ? 1.f : 0.f;
                v[j] = (h >= 1.f) ? 0.f : h;
            }
            __syncthreads();
            #pragma unroll
            for (int j = 0; j < 16; ++j) T[c_r0 + 4 * j][n_l] = s[j];
            __syncthreads();
            const size_t ob = (size_t)(t * BB + b) * NP * CC + (size_t)(n0 + n_r) * CC + c_base + cq;
            u16 u[16];
            #pragma unroll
            for (int m = 0; m < 16; ++m) u[m] = (T[cq + m][n_r] != 0.f) ? 0x3F80 : 0;
            uint4 q0 = make_uint4(pk2(u[0],u[1]),  pk2(u[2],u[3]),  pk2(u[4],u[5]),  pk2(u[6],u[7]));
            uint4 q1 = make_uint4(pk2(u[8],u[9]),  pk2(u[10],u[11]),pk2(u[12],u[13]),pk2(u[14],u[15]));
            *(uint4*)(XS + ob)     = q0;
            *(uint4*)(XS + ob + 8) = q1;
            __syncthreads();
        }
    }
}

// ---------------- fused QKV GEMM + BN + LIF -> bf16 spikes [tb][n][C] ----------------
// block = (wtile: 64 o-cols, stile: 128 n-rows, b); t-loop inside with LIF states in regs.
// G=0: q path (q_on/q_off/push-pull LIF); G=1,2: plain LIF (k, v).
template<int G>
__global__ __launch_bounds__(256) void k_gemm_lif(const u16* __restrict__ S, const u16* __restrict__ W3,
                                                  const float* __restrict__ scale, const float* __restrict__ shift,
                                                  u16* __restrict__ Sout, const float* __restrict__ pw_,
                                                  const float* __restrict__ pl_, const float* __restrict__ pb_) {
    __shared__ __align__(16) u16 Xt[128 * 32];      // spike tile [128 n][32 k]
    __shared__ __align__(16) u16 Wt[3][64 * 32];    // W tile per split [64 o][32 k]
    const int tid  = threadIdx.x;
    const int lane = tid & 63;
    const int w    = tid >> 6;
    const int wtile = blockIdx.x;   // 0..7 -> o0 = wtile*64
    const int stile = blockIdx.y;   // 0..1 -> n0 = stile*128
    const int b     = blockIdx.z;   // 0..31
    const u16* Wb = W3 + (size_t)G * 786432 + (size_t)(wtile * 64) * CC;
    const float* scl = scale + G * 512;
    const float* shf = shift + G * 512;

    const int lrow   = lane >> 2;
    const int lchunk = (lane & 3) * 8;
    const int l15  = lane & 15;
    const int kb8  = (lane >> 4) * 8;
    const int quad4 = (lane >> 4) * 4;
    const int wm = (w >> 1) * 64;   // n-offset of wave tile
    const int wn = (w & 1) * 32;    // o-offset of wave tile

    float pw = 0.f, pl = 0.f, pb = 0.f;
    if constexpr (G == 0) {
        pw = log1pf(expf(pw_[0]));
        pl = log1pf(expf(pl_[0]));
        pb = pb_[0];
    }

    // LIF membrane states in C/D fragment layout
    float st0[4][2][4];
    float st1[4][2][4];
    float st2[4][2][4];
    #pragma unroll
    for (int mt = 0; mt < 4; ++mt)
        #pragma unroll
        for (int nt = 0; nt < 2; ++nt)
            #pragma unroll
            for (int r = 0; r < 4; ++r) {
                st0[mt][nt][r] = 0.f;
                if constexpr (G == 0) { st1[mt][nt][r] = 0.f; st2[mt][nt][r] = 0.f; }
            }

    for (int t = 0; t < TT; ++t) {
        const int tb = t * BB + b;
        const u16* Sb = S + ((size_t)tb * NP + (size_t)stile * 128) * CC;
        f32x4 acc[4][2];
        f32x4 zz = {0.f, 0.f, 0.f, 0.f};
        #pragma unroll
        for (int mt = 0; mt < 4; ++mt) { acc[mt][0] = zz; acc[mt][1] = zz; }

        for (int c0 = 0; c0 < CC; c0 += 32) {
            __syncthreads();
            gld16(Sb + (size_t)(w * 32 + lrow) * CC + c0 + lchunk,      &Xt[(w * 32) * 32]);
            gld16(Sb + (size_t)(w * 32 + 16 + lrow) * CC + c0 + lchunk, &Xt[(w * 32 + 16) * 32]);
            #pragma unroll
            for (int i = 0; i < 3; ++i) {
                int lin = w * 3 + i;
                int s = lin >> 2, grp = lin & 3;
                gld16(Wb + (size_t)s * 262144 + (size_t)(grp * 16 + lrow) * CC + c0 + lchunk,
                      &Wt[s][(grp * 16) * 32]);
            }
            __syncthreads();
            bf16x8 af[4];
            #pragma unroll
            for (int i = 0; i < 4; ++i) af[i] = *(const bf16x8*)&Xt[(wm + i * 16 + l15) * 32 + kb8];
            #pragma unroll
            for (int s = 0; s < 3; ++s) {
                bf16x8 bf2[2];
                #pragma unroll
                for (int j = 0; j < 2; ++j) bf2[j] = *(const bf16x8*)&Wt[s][(wn + j * 16 + l15) * 32 + kb8];
                #pragma unroll
                for (int mt = 0; mt < 4; ++mt)
                    #pragma unroll
                    for (int nt = 0; nt < 2; ++nt)
                        acc[mt][nt] = __builtin_amdgcn_mfma_f32_16x16x32_bf16(af[mt], bf2[nt], acc[mt][nt], 0, 0, 0);
            }
        }

        // epilogue: BN + LIF, emit bf16 spikes
        u16* Ob = Sout + (size_t)tb * NP * CC;
        #pragma unroll
        for (int nt = 0; nt < 2; ++nt) {
            int o = wtile * 64 + wn + nt * 16 + l15;
            float sc = scl[o], sh = shf[o];
            #pragma unroll
            for (int mt = 0; mt < 4; ++mt) {
                int nr = stile * 128 + wm + mt * 16 + quad4;
                #pragma unroll
                for (int r = 0; r < 4; ++r) {
                    float y = acc[mt][nt][r] * sc + sh;
                    bool sp;
                    if constexpr (G == 0) {
                        float v0 = st0[mt][nt][r];
                        float h1 = v0 + (y - v0) * 0.5f;
                        bool s1 = (h1 >= 1.f);
                        st0[mt][nt][r] = s1 ? 0.f : h1;
                        float v1 = st1[mt][nt][r];
                        float h2 = v1 + (-y - v1) * 0.5f;
                        bool s2 = (h2 >= 1.f);
                        st1[mt][nt][r] = s2 ? 0.f : h2;
                        float df = pw * (s1 ? 1.f : 0.f) - pl * (s2 ? 1.f : 0.f) + pb;
                        float v2 = st2[mt][nt][r];
                        float h3 = v2 + (df - v2) * 0.5f;
                        sp = (h3 >= 1.f);
                        st2[mt][nt][r] = sp ? 0.f : h3;
                    } else {
                        float v0 = st0[mt][nt][r];
                        float h = v0 + (y - v0) * 0.5f;
                        sp = (h >= 1.f);
                        st0[mt][nt][r] = sp ? 0.f : h;
                    }
                    Ob[(size_t)(nr + r) * CC + o] = sp ? 0x3F80 : 0;
                }
            }
        }
    }
}

// ---------------- MFMA attention per (tb,h): kv = K^T V ; O = 0.125 * Q_pp kv -> bf16 [tb][n][C] ----------------
// Inputs: bf16 spike tensors [tb][n(256)][C].
__global__ __launch_bounds__(256) void k_attn(const u16* __restrict__ Q, const u16* __restrict__ K,
                                              const u16* __restrict__ V, u16* __restrict__ OS) {
    __shared__ __align__(16) u16 sm[19584];   // max(2*64*136, 208*72 + 64*72) u16 = 39168 B
    u16* Kt  = sm;            // phase A: [64 d][136]
    u16* Vt  = sm + 8704;     // phase A: [64 e][136]
    u16* Qs  = sm;            // phase B: [208 n][72]
    u16* kvT = sm + 14976;    // phase B: [64 e][72]

    const int tid = threadIdx.x;
    const int tb  = blockIdx.x >> 3;
    const int h   = blockIdx.x & 7;
    const size_t gb = (size_t)tb * (NP * CC) + (size_t)h * HD;

    const int srow = tid >> 2;            // 0..63 staging row
    const int sdq  = (tid & 3) * 16;      // 0,16,32,48

    const int lane = tid & 63;
    const int w    = tid >> 6;
    const int l15  = lane & 15;
    const int kb8  = (lane >> 4) * 8;
    const int quad = (lane >> 4) * 4;
    const int dh = (w >> 1) * 32, eh = (w & 1) * 32;

    f32x4 accA[2][2];
    f32x4 zz = {0.f, 0.f, 0.f, 0.f};
    #pragma unroll
    for (int i = 0; i < 2; ++i)
        #pragma unroll
        for (int j = 0; j < 2; ++j) accA[i][j] = zz;

    const uint4 z4 = make_uint4(0, 0, 0, 0);

    // ---- phase A over 2 n-chunks of 128
    #pragma unroll
    for (int ch = 0; ch < 2; ++ch) {
        if (ch) __syncthreads();
        #pragma unroll
        for (int c = 0; c < 2; ++c) {
            int n  = ch * 128 + c * 64 + srow;
            int nl = c * 64 + srow;
            bool valid = n < NN;
            const u16* kr = K + gb + (size_t)n * CC + sdq;
            const u16* vr = V + gb + (size_t)n * CC + sdq;
            uint4 ka = valid ? *(const uint4*)kr : z4;
            uint4 kb2 = valid ? *(const uint4*)(kr + 8) : z4;
            uint4 va = valid ? *(const uint4*)vr : z4;
            uint4 vb2 = valid ? *(const uint4*)(vr + 8) : z4;
            u32 kwv[8] = {ka.x, ka.y, ka.z, ka.w, kb2.x, kb2.y, kb2.z, kb2.w};
            u32 vwv[8] = {va.x, va.y, va.z, va.w, vb2.x, vb2.y, vb2.z, vb2.w};
            #pragma unroll
            for (int i = 0; i < 8; ++i) {
                Kt[(sdq + 2 * i) * 136 + nl]     = (u16)(kwv[i] & 0xFFFF);
                Kt[(sdq + 2 * i + 1) * 136 + nl] = (u16)(kwv[i] >> 16);
                Vt[(sdq + 2 * i) * 136 + nl]     = (u16)(vwv[i] & 0xFFFF);
                Vt[(sdq + 2 * i + 1) * 136 + nl] = (u16)(vwv[i] >> 16);
            }
        }
        __syncthreads();
        #pragma unroll
        for (int k0 = 0; k0 < 128; k0 += 32) {
            bf16x8 af[2], bv[2];
            #pragma unroll
            for (int i = 0; i < 2; ++i) {
                af[i] = *(const bf16x8*)&Kt[(dh + i * 16 + l15) * 136 + k0 + kb8];
                bv[i] = *(const bf16x8*)&Vt[(eh + i * 16 + l15) * 136 + k0 + kb8];
            }
            #pragma unroll
            for (int i = 0; i < 2; ++i)
                #pragma unroll
                for (int j = 0; j < 2; ++j)
                    accA[i][j] = __builtin_amdgcn_mfma_f32_16x16x32_bf16(af[i], bv[j], accA[i][j], 0, 0, 0);
        }
    }
    __syncthreads();   // all waves done with Kt/Vt before overwrite

    // ---- write kv^T (bf16, exact: integers <= 196) and stage Q
    #pragma unroll
    for (int i = 0; i < 2; ++i)
        #pragma unroll
        for (int j = 0; j < 2; ++j)
            #pragma unroll
            for (int r = 0; r < 4; ++r) {
                int e = eh + j * 16 + l15;
                int d = dh + i * 16 + quad + r;
                kvT[e * 72 + d] = f2bf(accA[i][j][r]);
            }
    #pragma unroll
    for (int p = 0; p < 4; ++p) {
        int n = p * 64 + srow;
        if (n < 208) {
            const u16* qr = Q + gb + (size_t)n * CC + sdq;
            uint4 qa  = *(const uint4*)qr;
            uint4 qb2 = *(const uint4*)(qr + 8);
            u32 qwv[8] = {qa.x, qa.y, qa.z, qa.w, qb2.x, qb2.y, qb2.z, qb2.w};
            #pragma unroll
            for (int i = 0; i < 8; ++i) {
                Qs[n * 72 + sdq + 2 * i]     = (u16)(qwv[i] & 0xFFFF);
                Qs[n * 72 + sdq + 2 * i + 1] = (u16)(qwv[i] >> 16);
            }
        }
    }
    __syncthreads();

    // ---- phase B: wave w owns e-tile [w*16, w*16+16)
    bf16x8 bq0 = *(const bf16x8*)&kvT[(w * 16 + l15) * 72 + 0  + kb8];
    bf16x8 bq1 = *(const bf16x8*)&kvT[(w * 16 + l15) * 72 + 32 + kb8];
    u16* ob = OS + (size_t)tb * (NP * CC) + (size_t)h * HD + w * 16 + l15;
    #pragma unroll
    for (int nt = 0; nt < 13; ++nt) {
        f32x4 acc = zz;
        bf16x8 a0 = *(const bf16x8*)&Qs[(nt * 16 + l15) * 72 + 0  + kb8];
        bf16x8 a1 = *(const bf16x8*)&Qs[(nt * 16 + l15) * 72 + 32 + kb8];
        acc = __builtin_amdgcn_mfma_f32_16x16x32_bf16(a0, bq0, acc, 0, 0, 0);
        acc = __builtin_amdgcn_mfma_f32_16x16x32_bf16(a1, bq1, acc, 0, 0, 0);
        #pragma unroll
        for (int r = 0; r < 4; ++r) {
            int n = nt * 16 + quad + r;
            if (n < NN) ob[(size_t)n * CC] = f2bf(acc[r] * 0.125f);
        }
    }
}

// ---------------- attn LIF (vth=0.5) in-place on bf16 ----------------
__global__ __launch_bounds__(256) void k_attn_lif(u16* __restrict__ OS) {
    size_t idx = (size_t)blockIdx.x * 256 + threadIdx.x;
    float v = 0.f;
    #pragma unroll
    for (int t = 0; t < TT; ++t) {
        size_t off = idx + (size_t)t * TSTRIDE;
        float xv = bf2f(OS[off]);
        float h = v + (xv - v) * 0.5f;
        bool s = (h >= 0.5f);
        v = s ? 0.f : h;
        OS[off] = s ? 0x3F80 : 0;
    }
}

// ---------------- final projection GEMM: out[tb][o][n<196] = BN(W p x spikes^T) ----------------
__global__ __launch_bounds__(256) void k_gemm_proj(const u16* __restrict__ S, const u16* __restrict__ W3,
                                                   const float* __restrict__ scale, const float* __restrict__ shift,
                                                   float* __restrict__ Y) {
    __shared__ __align__(16) u16 Xt[128 * 32];
    __shared__ __align__(16) u16 Wt[3][128 * 32];
    const int tid  = threadIdx.x;
    const int lane = tid & 63;
    const int w    = tid >> 6;
    const int wtile = blockIdx.x;   // 0..3 (o)
    const int stile = blockIdx.y;   // 0..1 (n)
    const int tb    = blockIdx.z;
    const u16* Sb = S + (size_t)tb * NP * CC + (size_t)(stile * 128) * CC;
    const u16* Wb = W3 + (size_t)(wtile * 128) * CC;

    const int lrow   = lane >> 2;
    const int lchunk = (lane & 3) * 8;
    const int l15 = lane & 15;
    const int kb  = (lane >> 4) * 8;
    const int wm = (w >> 1) * 64, wn = (w & 1) * 64;

    f32x4 acc[4][4];
    f32x4 zz = {0.f, 0.f, 0.f, 0.f};
    #pragma unroll
    for (int i = 0; i < 4; ++i)
        #pragma unroll
        for (int j = 0; j < 4; ++j) acc[i][j] = zz;

    for (int c0 = 0; c0 < CC; c0 += 32) {
        __syncthreads();
        #pragma unroll
        for (int cpy = 0; cpy < 2; ++cpy) {
            int r = w * 32 + cpy * 16 + lrow;
            gld16(Sb + (size_t)r * CC + c0 + lchunk, &Xt[(w * 32 + cpy * 16) * 32]);
        }
        #pragma unroll
        for (int s = 0; s < 3; ++s)
            #pragma unroll
            for (int cpy = 0; cpy < 2; ++cpy) {
                int r = w * 32 + cpy * 16 + lrow;
                gld16(Wb + (size_t)s * CC * CC + (size_t)r * CC + c0 + lchunk,
                      &Wt[s][(w * 32 + cpy * 16) * 32]);
            }
        __syncthreads();

        bf16x8 sf[4];
        #pragma unroll
        for (int i = 0; i < 4; ++i) sf[i] = *(const bf16x8*)&Xt[(wn + i * 16 + l15) * 32 + kb];
        #pragma unroll
        for (int s = 0; s < 3; ++s) {
            bf16x8 wf[4];
            #pragma unroll
            for (int i = 0; i < 4; ++i) wf[i] = *(const bf16x8*)&Wt[s][(wm + i * 16 + l15) * 32 + kb];
            #pragma unroll
            for (int mt = 0; mt < 4; ++mt)
                #pragma unroll
                for (int nt = 0; nt < 4; ++nt)
                    acc[mt][nt] = __builtin_amdgcn_mfma_f32_16x16x32_bf16(wf[mt], sf[nt], acc[mt][nt], 0, 0, 0);
        }
    }

    float* Yb = Y + (size_t)tb * CC * NN;
    #pragma unroll
    for (int mt = 0; mt < 4; ++mt) {
        int o0 = wtile * 128 + wm + mt * 16 + (lane >> 4) * 4;
        #pragma unroll
        for (int nt = 0; nt < 4; ++nt) {
            int n = stile * 128 + wn + nt * 16 + l15;
            if (n < NN) {
                #pragma unroll
                for (int r = 0; r < 4; ++r)
                    Yb[(size_t)(o0 + r) * NN + n] = acc[mt][nt][r] * scale[o0 + r] + shift[o0 + r];
            }
        }
    }
}

extern "C" void kernel_launch(void* const* d_in, const int* in_sizes, int n_in,
                              void* d_out, int out_size, void* d_ws, size_t ws_size,
                              hipStream_t stream) {
    const float* x    = (const float*)d_in[0];
    const float* q_cw = (const float*)d_in[1];
    const float* q_cb = (const float*)d_in[2];
    const float* q_bg = (const float*)d_in[3];
    const float* q_bb = (const float*)d_in[4];
    const float* q_bm = (const float*)d_in[5];
    const float* q_bv = (const float*)d_in[6];
    const float* k_cw = (const float*)d_in[7];
    const float* k_cb = (const float*)d_in[8];
    const float* k_bg = (const float*)d_in[9];
    const float* k_bb = (const float*)d_in[10];
    const float* k_bm = (const float*)d_in[11];
    const float* k_bv = (const float*)d_in[12];
    const float* v_cw = (const float*)d_in[13];
    const float* v_cb = (const float*)d_in[14];
    const float* v_bg = (const float*)d_in[15];
    const float* v_bb = (const float*)d_in[16];
    const float* v_bm = (const float*)d_in[17];
    const float* v_bv = (const float*)d_in[18];
    const float* p_cw = (const float*)d_in[19];
    const float* p_cb = (const float*)d_in[20];
    const float* p_bg = (const float*)d_in[21];
    const float* p_bb = (const float*)d_in[22];
    const float* p_bm = (const float*)d_in[23];
    const float* p_bv = (const float*)d_in[24];
    const float* pshw = (const float*)d_in[25];
    const float* pllw = (const float*)d_in[26];
    const float* ppb  = (const float*)d_in[27];
    float* out = (float*)d_out;

    // ws map (bf16 spike buffers): XS/OS 32MB | QS 32MB | KS 32MB | VS 32MB | W3 6MB | SS/SH
    if (ws_size < (size_t)140 * 1024 * 1024) return;
    char* W = (char*)d_ws;
    u16* XS = (u16*)W;                              // head spikes; later reused as attn output OS
    u16* QS = (u16*)(W + ((size_t)32 << 20));
    u16* KS = (u16*)(W + ((size_t)64 << 20));
    u16* VS = (u16*)(W + ((size_t)96 << 20));
    u16* W3 = (u16*)(W + ((size_t)128 << 20));
    float* SS = (float*)(W + ((size_t)128 << 20) + 6291456);  // scale[4][512]
    float* SH = SS + 2048;                                     // shift[4][512]

    k_prep_w<<<4096, 256, 0, stream>>>(q_cw, k_cw, v_cw, p_cw, W3);
    k_prep_bn4<<<8, 256, 0, stream>>>(q_cb, q_bg, q_bb, q_bm, q_bv,
                                      k_cb, k_bg, k_bb, k_bm, k_bv,
                                      v_cb, v_bg, v_bb, v_bm, v_bv,
                                      p_cb, p_bg, p_bb, p_bm, p_bv, SS, SH);

    k_head_lif<<<dim3(4, 32, 2), 256, 0, stream>>>(x, XS);

    dim3 fg(8, 2, BB);
    k_gemm_lif<0><<<fg, 256, 0, stream>>>(XS, W3, SS, SH, QS, pshw, pllw, ppb);
    k_gemm_lif<1><<<fg, 256, 0, stream>>>(XS, W3, SS, SH, KS, pshw, pllw, ppb);
    k_gemm_lif<2><<<fg, 256, 0, stream>>>(XS, W3, SS, SH, VS, pshw, pllw, ppb);

    k_attn<<<TBB * NHH, 256, 0, stream>>>(QS, KS, VS, XS);   // OS overwrites XS (dead)
    k_attn_lif<<<16384, 256, 0, stream>>>(XS);

    k_gemm_proj<<<dim3(4, 2, TBB), 256, 0, stream>>>(XS, W3 + 3 * 786432, SS + 1536, SH + 1536, out);
}

// Round 5
// 526.197 us; speedup vs baseline: 1.0033x; 1.0033x over previous
//
#include <hip/hip_runtime.h>
#include <hip/hip_bf16.h>
#include <math.h>

typedef unsigned short u16;
typedef unsigned int   u32;

#define CC 512
#define NN 196
#define NP 256
#define TT 4
#define BB 32
#define TBB 128
#define NHH 8
#define HD 64

typedef __attribute__((ext_vector_type(8))) short bf16x8;
typedef __attribute__((ext_vector_type(4))) float f32x4;

#define TSTRIDE   ((size_t)BB * NP * CC)          // 4,194,304 elems per t-slice

__device__ __forceinline__ u16 f2bf(float f) {
    __hip_bfloat16 h = __float2bfloat16(f);
    return *(u16*)&h;
}
__device__ __forceinline__ float bf2f(u16 u) {
    u32 ui = ((u32)u) << 16;
    return __uint_as_float(ui);
}
__device__ __forceinline__ u32 pk2(u16 a, u16 b) { return (u32)a | ((u32)b << 16); }

// async 16B/lane global->LDS; lds base must be wave-uniform
__device__ __forceinline__ void gld16(const void* g, void* l) {
    __builtin_amdgcn_global_load_lds(
        (const __attribute__((address_space(1))) void*)g,
        (__attribute__((address_space(3))) void*)l, 16, 0, 0);
}

// ---------------- prep: split fp32 weights into 3 exact bf16 planes ----------------
__global__ __launch_bounds__(256) void k_prep_w(const float* __restrict__ qw, const float* __restrict__ kw,
                                                const float* __restrict__ vw, const float* __restrict__ pw,
                                                u16* __restrict__ W3) {
    size_t idx = (size_t)blockIdx.x * 256 + threadIdx.x;   // 4 * 262144
    int g = (int)(idx >> 18);
    size_t rem = idx & 262143;
    const float* Ws = (g == 0) ? qw : (g == 1) ? kw : (g == 2) ? vw : pw;
    float w  = Ws[rem];
    u16 u0 = f2bf(w);      float b0 = bf2f(u0);
    float r1 = w - b0;
    u16 u1 = f2bf(r1);     float b1 = bf2f(u1);
    float r2 = r1 - b1;
    u16 u2 = f2bf(r2);
    size_t base = (size_t)g * 786432 + rem;
    W3[base] = u0; W3[base + 262144] = u1; W3[base + 524288] = u2;
}

// all 4 BN param groups in one launch: grid 8 x 256 = 2048 = 4 groups x 512
__global__ __launch_bounds__(256) void k_prep_bn4(
    const float* __restrict__ cb0, const float* __restrict__ bg0, const float* __restrict__ bb0,
    const float* __restrict__ bm0, const float* __restrict__ bv0,
    const float* __restrict__ cb1, const float* __restrict__ bg1, const float* __restrict__ bb1,
    const float* __restrict__ bm1, const float* __restrict__ bv1,
    const float* __restrict__ cb2, const float* __restrict__ bg2, const float* __restrict__ bb2,
    const float* __restrict__ bm2, const float* __restrict__ bv2,
    const float* __restrict__ cb3, const float* __restrict__ bg3, const float* __restrict__ bb3,
    const float* __restrict__ bm3, const float* __restrict__ bv3,
    float* __restrict__ SS, float* __restrict__ SH) {
    int idx = blockIdx.x * 256 + threadIdx.x;
    int g = idx >> 9, o = idx & 511;
    const float* cb = g == 0 ? cb0 : g == 1 ? cb1 : g == 2 ? cb2 : cb3;
    const float* bg = g == 0 ? bg0 : g == 1 ? bg1 : g == 2 ? bg2 : bg3;
    const float* bb = g == 0 ? bb0 : g == 1 ? bb1 : g == 2 ? bb2 : bb3;
    const float* bm = g == 0 ? bm0 : g == 1 ? bm1 : g == 2 ? bm2 : bm3;
    const float* bv = g == 0 ? bv0 : g == 1 ? bv1 : g == 2 ? bv2 : bv3;
    float inv = bg[o] / sqrtf(bv[o] + 1e-5f);
    SS[g * 512 + o] = inv;
    SH[g * 512 + o] = (cb[o] - bm[o]) * inv + bb[o];
}

// ---------------- head LIF + transpose: x[t][b][C][196] -> XS[tb][n(256)][C] bf16 spikes ----------------
__global__ __launch_bounds__(256) void k_head_lif(const float* __restrict__ x, u16* __restrict__ XS) {
    __shared__ float T[64][65];
    const int tid = threadIdx.x;
    const int n0 = blockIdx.x * 64;       // 0..3 * 64
    const int b  = blockIdx.y;            // 0..31
    const int ch = blockIdx.z;            // 0..1
    const int n_l = tid & 63;
    const int c_r0 = tid >> 6;            // 0..3
    const int n_r = tid >> 2;             // 0..63
    const int cq  = (tid & 3) * 16;

    for (int cc = 0; cc < 4; ++cc) {
        const int c_base = ch * 256 + cc * 64;
        float v[16];
        #pragma unroll
        for (int j = 0; j < 16; ++j) v[j] = 0.f;
        for (int t = 0; t < TT; ++t) {
            const size_t xb = ((size_t)(t * BB + b) * CC + c_base) * NN;
            float s[16];
            #pragma unroll
            for (int j = 0; j < 16; ++j) {
                int c_l = c_r0 + 4 * j;
                float xv = (n0 + n_l < NN) ? x[xb + (size_t)c_l * NN + n0 + n_l] : 0.f;
                float h = v[j] + (xv - v[j]) * 0.5f;
                s[j] = (h >= 1.f) ? 1.f : 0.f;
                v[j] = (h >= 1.f) ? 0.f : h;
            }
            __syncthreads();
            #pragma unroll
            for (int j = 0; j < 16; ++j) T[c_r0 + 4 * j][n_l] = s[j];
            __syncthreads();
            const size_t ob = (size_t)(t * BB + b) * NP * CC + (size_t)(n0 + n_r) * CC + c_base + cq;
            u16 u[16];
            #pragma unroll
            for (int m = 0; m < 16; ++m) u[m] = (T[cq + m][n_r] != 0.f) ? 0x3F80 : 0;
            uint4 q0 = make_uint4(pk2(u[0],u[1]),  pk2(u[2],u[3]),  pk2(u[4],u[5]),  pk2(u[6],u[7]));
            uint4 q1 = make_uint4(pk2(u[8],u[9]),  pk2(u[10],u[11]),pk2(u[12],u[13]),pk2(u[14],u[15]));
            *(uint4*)(XS + ob)     = q0;
            *(uint4*)(XS + ob + 8) = q1;
            __syncthreads();
        }
    }
}

// ---------------- merged QKV MFMA GEMM, 3-split bf16 weights ----------------
// blockIdx.x = g*4 + wtile (g selects q/k/v); D[m=n][n'=o] -> Y fp32 [tb][256][512] at g*64MB
__global__ __launch_bounds__(256) void k_gemm_qkv(const u16* __restrict__ S, const u16* __restrict__ W3,
                                                  const float* __restrict__ scale, const float* __restrict__ shift,
                                                  float* __restrict__ Y) {
    __shared__ __align__(16) u16 Xt[128 * 32];
    __shared__ __align__(16) u16 Wt[3][128 * 32];
    const int tid  = threadIdx.x;
    const int lane = tid & 63;
    const int w    = tid >> 6;
    const int g     = blockIdx.x >> 2;
    const int wtile = blockIdx.x & 3;
    const int stile = blockIdx.y;   // spike-row tile (n), 0..1
    const int tb    = blockIdx.z;
    const u16* Sb = S + (size_t)tb * NP * CC + (size_t)(stile * 128) * CC;
    const u16* Wb = W3 + (size_t)g * 786432 + (size_t)(wtile * 128) * CC;
    const float* scl = scale + g * 512;
    const float* shf = shift + g * 512;
    float* Yg = Y + (size_t)g * 16777216;

    const int lrow   = lane >> 2;        // 0..15 within 16-row wave chunk
    const int lchunk = (lane & 3) * 8;   // bf16 elems
    const int l15 = lane & 15;
    const int kb  = (lane >> 4) * 8;
    const int wm = (w >> 1) * 64, wn = (w & 1) * 64;

    f32x4 acc[4][4];
    f32x4 zz = {0.f, 0.f, 0.f, 0.f};
    #pragma unroll
    for (int i = 0; i < 4; ++i)
        #pragma unroll
        for (int j = 0; j < 4; ++j) acc[i][j] = zz;

    for (int c0 = 0; c0 < CC; c0 += 32) {
        __syncthreads();
        #pragma unroll
        for (int cpy = 0; cpy < 2; ++cpy) {
            int r = w * 32 + cpy * 16 + lrow;
            gld16(Sb + (size_t)r * CC + c0 + lchunk, &Xt[(w * 32 + cpy * 16) * 32]);
        }
        #pragma unroll
        for (int s = 0; s < 3; ++s)
            #pragma unroll
            for (int cpy = 0; cpy < 2; ++cpy) {
                int r = w * 32 + cpy * 16 + lrow;
                gld16(Wb + (size_t)s * CC * CC + (size_t)r * CC + c0 + lchunk,
                      &Wt[s][(w * 32 + cpy * 16) * 32]);
            }
        __syncthreads();

        bf16x8 sf[4];
        #pragma unroll
        for (int i = 0; i < 4; ++i) sf[i] = *(const bf16x8*)&Xt[(wm + i * 16 + l15) * 32 + kb];
        #pragma unroll
        for (int s = 0; s < 3; ++s) {
            bf16x8 wf[4];
            #pragma unroll
            for (int i = 0; i < 4; ++i) wf[i] = *(const bf16x8*)&Wt[s][(wn + i * 16 + l15) * 32 + kb];
            #pragma unroll
            for (int mt = 0; mt < 4; ++mt)
                #pragma unroll
                for (int nt = 0; nt < 4; ++nt)
                    acc[mt][nt] = __builtin_amdgcn_mfma_f32_16x16x32_bf16(sf[mt], wf[nt], acc[mt][nt], 0, 0, 0);
        }
    }

    // epilogue: C/D layout col = lane&15, row = (lane>>4)*4 + reg
    float* Yb = Yg + (size_t)tb * NP * CC;
    #pragma unroll
    for (int nt = 0; nt < 4; ++nt) {
        int o = wtile * 128 + wn + nt * 16 + l15;
        float sc = scl[o], sh = shf[o];
        #pragma unroll
        for (int mt = 0; mt < 4; ++mt) {
            int r0 = stile * 128 + wm + mt * 16 + (lane >> 4) * 4;
            #pragma unroll
            for (int r = 0; r < 4; ++r)
                Yb[(size_t)(r0 + r) * CC + o] = acc[mt][nt][r] * sc + sh;
        }
    }
}

// ---------------- fused q_on/q_off/push-pull + k,v LIF ----------------
// In-place: reads fp32 y, writes the spike (0x3F80/0) into the LOW u16 of the same slot.
// Each thread owns its slots across t -> race-free single launch, no extra buffers.
__global__ __launch_bounds__(256) void k_qkv_lif(float* Q, float* K, float* V,
                                                 const float* __restrict__ pw_,
                                                 const float* __restrict__ pl_,
                                                 const float* __restrict__ pb_) {
    size_t idx = (size_t)blockIdx.x * 256 + threadIdx.x;
    float pw = log1pf(expf(pw_[0]));
    float pl = log1pf(expf(pl_[0]));
    float pb = pb_[0];
    float von = 0.f, voff = 0.f, vpp = 0.f, vk = 0.f, vv = 0.f;
    #pragma unroll
    for (int t = 0; t < TT; ++t) {
        size_t off = idx + (size_t)t * TSTRIDE;
        float qv = Q[off], kv = K[off], xv = V[off];
        float h;
        h = von  + ( qv - von ) * 0.5f; bool s1 = (h >= 1.f); von  = s1 ? 0.f : h;
        h = voff + (-qv - voff) * 0.5f; bool s2 = (h >= 1.f); voff = s2 ? 0.f : h;
        float diff = pw * (s1 ? 1.f : 0.f) - pl * (s2 ? 1.f : 0.f) + pb;
        h = vpp  + (diff - vpp) * 0.5f; bool sp = (h >= 1.f); vpp  = sp ? 0.f : h;
        h = vk   + ( kv - vk  ) * 0.5f; bool sk = (h >= 1.f); vk   = sk ? 0.f : h;
        h = vv   + ( xv - vv  ) * 0.5f; bool sv = (h >= 1.f); vv   = sv ? 0.f : h;
        ((u16*)&Q[off])[0] = sp ? 0x3F80 : 0;
        ((u16*)&K[off])[0] = sk ? 0x3F80 : 0;
        ((u16*)&V[off])[0] = sv ? 0x3F80 : 0;
    }
}

// ---------------- MFMA attention per (tb,h): kv = K^T V ; O = 0.125 * Q_pp kv -> bf16 [tb][n][C] ----------------
// Inputs: u32 views of the fp32 buffers; spike = low u16 of each slot.
__global__ __launch_bounds__(256) void k_attn(const u32* __restrict__ Q, const u32* __restrict__ K,
                                              const u32* __restrict__ V, u16* __restrict__ OS) {
    __shared__ __align__(16) u16 sm[19584];   // max(2*64*136, 208*72 + 64*72) u16 = 39168 B
    u16* Kt  = sm;            // phase A: [64 d][136]
    u16* Vt  = sm + 8704;     // phase A: [64 e][136]
    u16* Qs  = sm;            // phase B: [208 n][72]
    u16* kvT = sm + 14976;    // phase B: [64 e][72]

    const int tid = threadIdx.x;
    const int tb  = blockIdx.x >> 3;
    const int h   = blockIdx.x & 7;
    const size_t gb = (size_t)tb * (NP * CC) + (size_t)h * HD;

    const int srow = tid >> 2;            // 0..63 staging row
    const int sdq  = (tid & 3) * 16;      // 0,16,32,48

    const int lane = tid & 63;
    const int w    = tid >> 6;
    const int l15  = lane & 15;
    const int kb8  = (lane >> 4) * 8;
    const int quad = (lane >> 4) * 4;
    const int dh = (w >> 1) * 32, eh = (w & 1) * 32;

    f32x4 accA[2][2];
    f32x4 zz = {0.f, 0.f, 0.f, 0.f};
    #pragma unroll
    for (int i = 0; i < 2; ++i)
        #pragma unroll
        for (int j = 0; j < 2; ++j) accA[i][j] = zz;

    const uint4 z4 = make_uint4(0, 0, 0, 0);

    // ---- phase A over 2 n-chunks of 128
    #pragma unroll
    for (int ch = 0; ch < 2; ++ch) {
        if (ch) __syncthreads();
        #pragma unroll
        for (int c = 0; c < 2; ++c) {
            int n  = ch * 128 + c * 64 + srow;
            int nl = c * 64 + srow;
            bool valid = n < NN;
            const u32* kr = K + gb + (size_t)n * CC + sdq;
            const u32* vr = V + gb + (size_t)n * CC + sdq;
            uint4 kq[4], vq[4];
            #pragma unroll
            for (int q = 0; q < 4; ++q) {
                kq[q] = valid ? *(const uint4*)(kr + 4 * q) : z4;
                vq[q] = valid ? *(const uint4*)(vr + 4 * q) : z4;
            }
            const u32* kw = (const u32*)kq;
            const u32* vw = (const u32*)vq;
            #pragma unroll
            for (int i = 0; i < 16; ++i) {
                Kt[(sdq + i) * 136 + nl] = (u16)(kw[i] & 0xFFFF);
                Vt[(sdq + i) * 136 + nl] = (u16)(vw[i] & 0xFFFF);
            }
        }
        __syncthreads();
        #pragma unroll
        for (int k0 = 0; k0 < 128; k0 += 32) {
            bf16x8 af[2], bv[2];
            #pragma unroll
            for (int i = 0; i < 2; ++i) {
                af[i] = *(const bf16x8*)&Kt[(dh + i * 16 + l15) * 136 + k0 + kb8];
                bv[i] = *(const bf16x8*)&Vt[(eh + i * 16 + l15) * 136 + k0 + kb8];
            }
            #pragma unroll
            for (int i = 0; i < 2; ++i)
                #pragma unroll
                for (int j = 0; j < 2; ++j)
                    accA[i][j] = __builtin_amdgcn_mfma_f32_16x16x32_bf16(af[i], bv[j], accA[i][j], 0, 0, 0);
        }
    }
    __syncthreads();   // all waves done with Kt/Vt before overwrite

    // ---- write kv^T (bf16, exact: integers <= 196) and stage Q
    #pragma unroll
    for (int i = 0; i < 2; ++i)
        #pragma unroll
        for (int j = 0; j < 2; ++j)
            #pragma unroll
            for (int r = 0; r < 4; ++r) {
                int e = eh + j * 16 + l15;
                int d = dh + i * 16 + quad + r;
                kvT[e * 72 + d] = f2bf(accA[i][j][r]);
            }
    #pragma unroll
    for (int p = 0; p < 4; ++p) {
        int n = p * 64 + srow;
        if (n < 208) {
            const u32* qr = Q + gb + (size_t)n * CC + sdq;
            uint4 qq[4];
            #pragma unroll
            for (int q = 0; q < 4; ++q) qq[q] = *(const uint4*)(qr + 4 * q);
            const u32* qw = (const u32*)qq;
            #pragma unroll
            for (int i = 0; i < 16; ++i)
                Qs[n * 72 + sdq + i] = (u16)(qw[i] & 0xFFFF);
        }
    }
    __syncthreads();

    // ---- phase B: wave w owns e-tile [w*16, w*16+16)
    bf16x8 bq0 = *(const bf16x8*)&kvT[(w * 16 + l15) * 72 + 0  + kb8];
    bf16x8 bq1 = *(const bf16x8*)&kvT[(w * 16 + l15) * 72 + 32 + kb8];
    u16* ob = OS + (size_t)tb * (NP * CC) + (size_t)h * HD + w * 16 + l15;
    #pragma unroll
    for (int nt = 0; nt < 13; ++nt) {
        f32x4 acc = zz;
        bf16x8 a0 = *(const bf16x8*)&Qs[(nt * 16 + l15) * 72 + 0  + kb8];
        bf16x8 a1 = *(const bf16x8*)&Qs[(nt * 16 + l15) * 72 + 32 + kb8];
        acc = __builtin_amdgcn_mfma_f32_16x16x32_bf16(a0, bq0, acc, 0, 0, 0);
        acc = __builtin_amdgcn_mfma_f32_16x16x32_bf16(a1, bq1, acc, 0, 0, 0);
        #pragma unroll
        for (int r = 0; r < 4; ++r) {
            int n = nt * 16 + quad + r;
            if (n < NN) ob[(size_t)n * CC] = f2bf(acc[r] * 0.125f);
        }
    }
}

// ---------------- attn LIF (vth=0.5) in-place on bf16 ----------------
__global__ __launch_bounds__(256) void k_attn_lif(u16* __restrict__ OS) {
    size_t idx = (size_t)blockIdx.x * 256 + threadIdx.x;
    float v = 0.f;
    #pragma unroll
    for (int t = 0; t < TT; ++t) {
        size_t off = idx + (size_t)t * TSTRIDE;
        float xv = bf2f(OS[off]);
        float h = v + (xv - v) * 0.5f;
        bool s = (h >= 0.5f);
        v = s ? 0.f : h;
        OS[off] = s ? 0x3F80 : 0;
    }
}

// ---------------- final projection GEMM: out[tb][o][n<196] = BN(W_p x spikes^T) ----------------
__global__ __launch_bounds__(256) void k_gemm_proj(const u16* __restrict__ S, const u16* __restrict__ W3,
                                                   const float* __restrict__ scale, const float* __restrict__ shift,
                                                   float* __restrict__ Y) {
    __shared__ __align__(16) u16 Xt[128 * 32];
    __shared__ __align__(16) u16 Wt[3][128 * 32];
    const int tid  = threadIdx.x;
    const int lane = tid & 63;
    const int w    = tid >> 6;
    const int wtile = blockIdx.x;   // 0..3 (o)
    const int stile = blockIdx.y;   // 0..1 (n)
    const int tb    = blockIdx.z;
    const u16* Sb = S + (size_t)tb * NP * CC + (size_t)(stile * 128) * CC;
    const u16* Wb = W3 + (size_t)(wtile * 128) * CC;

    const int lrow   = lane >> 2;
    const int lchunk = (lane & 3) * 8;
    const int l15 = lane & 15;
    const int kb  = (lane >> 4) * 8;
    const int wm = (w >> 1) * 64, wn = (w & 1) * 64;

    f32x4 acc[4][4];
    f32x4 zz = {0.f, 0.f, 0.f, 0.f};
    #pragma unroll
    for (int i = 0; i < 4; ++i)
        #pragma unroll
        for (int j = 0; j < 4; ++j) acc[i][j] = zz;

    for (int c0 = 0; c0 < CC; c0 += 32) {
        __syncthreads();
        #pragma unroll
        for (int cpy = 0; cpy < 2; ++cpy) {
            int r = w * 32 + cpy * 16 + lrow;
            gld16(Sb + (size_t)r * CC + c0 + lchunk, &Xt[(w * 32 + cpy * 16) * 32]);
        }
        #pragma unroll
        for (int s = 0; s < 3; ++s)
            #pragma unroll
            for (int cpy = 0; cpy < 2; ++cpy) {
                int r = w * 32 + cpy * 16 + lrow;
                gld16(Wb + (size_t)s * CC * CC + (size_t)r * CC + c0 + lchunk,
                      &Wt[s][(w * 32 + cpy * 16) * 32]);
            }
        __syncthreads();

        bf16x8 sf[4];
        #pragma unroll
        for (int i = 0; i < 4; ++i) sf[i] = *(const bf16x8*)&Xt[(wn + i * 16 + l15) * 32 + kb];
        #pragma unroll
        for (int s = 0; s < 3; ++s) {
            bf16x8 wf[4];
            #pragma unroll
            for (int i = 0; i < 4; ++i) wf[i] = *(const bf16x8*)&Wt[s][(wm + i * 16 + l15) * 32 + kb];
            #pragma unroll
            for (int mt = 0; mt < 4; ++mt)
                #pragma unroll
                for (int nt = 0; nt < 4; ++nt)
                    acc[mt][nt] = __builtin_amdgcn_mfma_f32_16x16x32_bf16(wf[mt], sf[nt], acc[mt][nt], 0, 0, 0);
        }
    }

    float* Yb = Y + (size_t)tb * CC * NN;
    #pragma unroll
    for (int mt = 0; mt < 4; ++mt) {
        int o0 = wtile * 128 + wm + mt * 16 + (lane >> 4) * 4;
        #pragma unroll
        for (int nt = 0; nt < 4; ++nt) {
            int n = stile * 128 + wn + nt * 16 + l15;
            if (n < NN) {
                #pragma unroll
                for (int r = 0; r < 4; ++r)
                    Yb[(size_t)(o0 + r) * NN + n] = acc[mt][nt][r] * scale[o0 + r] + shift[o0 + r];
            }
        }
    }
}

extern "C" void kernel_launch(void* const* d_in, const int* in_sizes, int n_in,
                              void* d_out, int out_size, void* d_ws, size_t ws_size,
                              hipStream_t stream) {
    const float* x    = (const float*)d_in[0];
    const float* q_cw = (const float*)d_in[1];
    const float* q_cb = (const float*)d_in[2];
    const float* q_bg = (const float*)d_in[3];
    const float* q_bb = (const float*)d_in[4];
    const float* q_bm = (const float*)d_in[5];
    const float* q_bv = (const float*)d_in[6];
    const float* k_cw = (const float*)d_in[7];
    const float* k_cb = (const float*)d_in[8];
    const float* k_bg = (const float*)d_in[9];
    const float* k_bb = (const float*)d_in[10];
    const float* k_bm = (const float*)d_in[11];
    const float* k_bv = (const float*)d_in[12];
    const float* v_cw = (const float*)d_in[13];
    const float* v_cb = (const float*)d_in[14];
    const float* v_bg = (const float*)d_in[15];
    const float* v_bb = (const float*)d_in[16];
    const float* v_bm = (const float*)d_in[17];
    const float* v_bv = (const float*)d_in[18];
    const float* p_cw = (const float*)d_in[19];
    const float* p_cb = (const float*)d_in[20];
    const float* p_bg = (const float*)d_in[21];
    const float* p_bb = (const float*)d_in[22];
    const float* p_bm = (const float*)d_in[23];
    const float* p_bv = (const float*)d_in[24];
    const float* pshw = (const float*)d_in[25];
    const float* pllw = (const float*)d_in[26];
    const float* ppb  = (const float*)d_in[27];
    float* out = (float*)d_out;

    // ws map: XS/OS bf16 32MB | Qf 64MB | Kf 64MB | Vf 64MB | W3 6MB | scale/shift (proven 242MB budget)
    if (ws_size < (size_t)242 * 1024 * 1024) return;
    char* W = (char*)d_ws;
    u16*   XS = (u16*)W;                             // head spikes; later reused as attn output OS
    float* Qf = (float*)(W + ((size_t)32 << 20));
    float* Kf = (float*)(W + ((size_t)96 << 20));
    float* Vf = (float*)(W + ((size_t)160 << 20));
    u16*   W3 = (u16*)(W + ((size_t)224 << 20));
    float* SS = (float*)(W + ((size_t)224 << 20) + 6291456);  // scale[4][512]
    float* SH = SS + 2048;                                     // shift[4][512]

    k_prep_w<<<4096, 256, 0, stream>>>(q_cw, k_cw, v_cw, p_cw, W3);
    k_prep_bn4<<<8, 256, 0, stream>>>(q_cb, q_bg, q_bb, q_bm, q_bv,
                                      k_cb, k_bg, k_bb, k_bm, k_bv,
                                      v_cb, v_bg, v_bb, v_bm, v_bv,
                                      p_cb, p_bg, p_bb, p_bm, p_bv, SS, SH);

    k_head_lif<<<dim3(4, 32, 2), 256, 0, stream>>>(x, XS);

    // merged Q/K/V projection: blockIdx.x = g*4 + wtile; Y offsets g*64MB (Qf,Kf,Vf contiguous)
    k_gemm_qkv<<<dim3(12, 2, TBB), 256, 0, stream>>>(XS, W3, SS, SH, Qf);

    // LIF writes spikes into the low u16 of each owned fp32 slot (in-place, race-free)
    k_qkv_lif<<<16384, 256, 0, stream>>>(Qf, Kf, Vf, pshw, pllw, ppb);

    k_attn<<<TBB * NHH, 256, 0, stream>>>((const u32*)Qf, (const u32*)Kf, (const u32*)Vf, XS);
    k_attn_lif<<<16384, 256, 0, stream>>>(XS);

    k_gemm_proj<<<dim3(4, 2, TBB), 256, 0, stream>>>(XS, W3 + 3 * 786432, SS + 1536, SH + 1536, out);
}

// Round 6
// 467.855 us; speedup vs baseline: 1.1285x; 1.1247x over previous
//
#include <hip/hip_runtime.h>
#include <hip/hip_bf16.h>
#include <math.h>

typedef unsigned short u16;
typedef unsigned int   u32;

#define CC 512
#define NN 196
#define NP 256
#define TT 4
#define BB 32
#define TBB 128
#define NHH 8
#define HD 64

typedef __attribute__((ext_vector_type(8))) short bf16x8;
typedef __attribute__((ext_vector_type(4))) float f32x4;

#define TSTRIDE   ((size_t)BB * NP * CC)          // 4,194,304 elems per t-slice
#define NVALID    ((size_t)BB * NN * CC)          // 32*196*512 = 3,211,264 valid elems per t

__device__ __forceinline__ u16 f2bf(float f) {
    __hip_bfloat16 h = __float2bfloat16(f);
    return *(u16*)&h;
}
__device__ __forceinline__ float bf2f(u16 u) {
    u32 ui = ((u32)u) << 16;
    return __uint_as_float(ui);
}
__device__ __forceinline__ u32 pk2(u16 a, u16 b) { return (u32)a | ((u32)b << 16); }

// async 16B/lane global->LDS; lds base must be wave-uniform
__device__ __forceinline__ void gld16(const void* g, void* l) {
    __builtin_amdgcn_global_load_lds(
        (const __attribute__((address_space(1))) void*)g,
        (__attribute__((address_space(3))) void*)l, 16, 0, 0);
}

// ---------------- prep: split fp32 weights into 3 exact bf16 planes ----------------
__global__ __launch_bounds__(256) void k_prep_w(const float* __restrict__ qw, const float* __restrict__ kw,
                                                const float* __restrict__ vw, const float* __restrict__ pw,
                                                u16* __restrict__ W3) {
    size_t idx = (size_t)blockIdx.x * 256 + threadIdx.x;   // 4 * 262144
    int g = (int)(idx >> 18);
    size_t rem = idx & 262143;
    const float* Ws = (g == 0) ? qw : (g == 1) ? kw : (g == 2) ? vw : pw;
    float w  = Ws[rem];
    u16 u0 = f2bf(w);      float b0 = bf2f(u0);
    float r1 = w - b0;
    u16 u1 = f2bf(r1);     float b1 = bf2f(u1);
    float r2 = r1 - b1;
    u16 u2 = f2bf(r2);
    size_t base = (size_t)g * 786432 + rem;
    W3[base] = u0; W3[base + 262144] = u1; W3[base + 524288] = u2;
}

// all 4 BN param groups in one launch: grid 8 x 256 = 2048 = 4 groups x 512
__global__ __launch_bounds__(256) void k_prep_bn4(
    const float* __restrict__ cb0, const float* __restrict__ bg0, const float* __restrict__ bb0,
    const float* __restrict__ bm0, const float* __restrict__ bv0,
    const float* __restrict__ cb1, const float* __restrict__ bg1, const float* __restrict__ bb1,
    const float* __restrict__ bm1, const float* __restrict__ bv1,
    const float* __restrict__ cb2, const float* __restrict__ bg2, const float* __restrict__ bb2,
    const float* __restrict__ bm2, const float* __restrict__ bv2,
    const float* __restrict__ cb3, const float* __restrict__ bg3, const float* __restrict__ bb3,
    const float* __restrict__ bm3, const float* __restrict__ bv3,
    float* __restrict__ SS, float* __restrict__ SH) {
    int idx = blockIdx.x * 256 + threadIdx.x;
    int g = idx >> 9, o = idx & 511;
    const float* cb = g == 0 ? cb0 : g == 1 ? cb1 : g == 2 ? cb2 : cb3;
    const float* bg = g == 0 ? bg0 : g == 1 ? bg1 : g == 2 ? bg2 : bg3;
    const float* bb = g == 0 ? bb0 : g == 1 ? bb1 : g == 2 ? bb2 : bb3;
    const float* bm = g == 0 ? bm0 : g == 1 ? bm1 : g == 2 ? bm2 : bm3;
    const float* bv = g == 0 ? bv0 : g == 1 ? bv1 : g == 2 ? bv2 : bv3;
    float inv = bg[o] / sqrtf(bv[o] + 1e-5f);
    SS[g * 512 + o] = inv;
    SH[g * 512 + o] = (cb[o] - bm[o]) * inv + bb[o];
}

// ---------------- head LIF + transpose: x[t][b][C][196] -> XS[tb][n(256)][C] bf16 spikes ----------------
__global__ __launch_bounds__(256) void k_head_lif(const float* __restrict__ x, u16* __restrict__ XS) {
    __shared__ float T[64][65];
    const int tid = threadIdx.x;
    const int n0 = blockIdx.x * 64;       // 0..3 * 64
    const int b  = blockIdx.y;            // 0..31
    const int ch = blockIdx.z;            // 0..1
    const int n_l = tid & 63;
    const int c_r0 = tid >> 6;            // 0..3
    const int n_r = tid >> 2;             // 0..63
    const int cq  = (tid & 3) * 16;

    for (int cc = 0; cc < 4; ++cc) {
        const int c_base = ch * 256 + cc * 64;
        float v[16];
        #pragma unroll
        for (int j = 0; j < 16; ++j) v[j] = 0.f;
        for (int t = 0; t < TT; ++t) {
            const size_t xb = ((size_t)(t * BB + b) * CC + c_base) * NN;
            float s[16];
            #pragma unroll
            for (int j = 0; j < 16; ++j) {
                int c_l = c_r0 + 4 * j;
                float xv = (n0 + n_l < NN) ? x[xb + (size_t)c_l * NN + n0 + n_l] : 0.f;
                float h = v[j] + (xv - v[j]) * 0.5f;
                s[j] = (h >= 1.f) ? 1.f : 0.f;
                v[j] = (h >= 1.f) ? 0.f : h;
            }
            __syncthreads();
            #pragma unroll
            for (int j = 0; j < 16; ++j) T[c_r0 + 4 * j][n_l] = s[j];
            __syncthreads();
            const size_t ob = (size_t)(t * BB + b) * NP * CC + (size_t)(n0 + n_r) * CC + c_base + cq;
            u16 u[16];
            #pragma unroll
            for (int m = 0; m < 16; ++m) u[m] = (T[cq + m][n_r] != 0.f) ? 0x3F80 : 0;
            uint4 q0 = make_uint4(pk2(u[0],u[1]),  pk2(u[2],u[3]),  pk2(u[4],u[5]),  pk2(u[6],u[7]));
            uint4 q1 = make_uint4(pk2(u[8],u[9]),  pk2(u[10],u[11]),pk2(u[12],u[13]),pk2(u[14],u[15]));
            *(uint4*)(XS + ob)     = q0;
            *(uint4*)(XS + ob + 8) = q1;
            __syncthreads();
        }
    }
}

// ---------------- merged QKV MFMA GEMM, 3-split bf16 weights ----------------
// blockIdx.x = g*4 + wtile (g selects q/k/v); D[m=n][n'=o] -> Y fp32 [tb][256][512] at g*64MB
__global__ __launch_bounds__(256) void k_gemm_qkv(const u16* __restrict__ S, const u16* __restrict__ W3,
                                                  const float* __restrict__ scale, const float* __restrict__ shift,
                                                  float* __restrict__ Y) {
    __shared__ __align__(16) u16 Xt[128 * 32];
    __shared__ __align__(16) u16 Wt[3][128 * 32];
    const int tid  = threadIdx.x;
    const int lane = tid & 63;
    const int w    = tid >> 6;
    const int g     = blockIdx.x >> 2;
    const int wtile = blockIdx.x & 3;
    const int stile = blockIdx.y;   // spike-row tile (n), 0..1
    const int tb    = blockIdx.z;
    const u16* Sb = S + (size_t)tb * NP * CC + (size_t)(stile * 128) * CC;
    const u16* Wb = W3 + (size_t)g * 786432 + (size_t)(wtile * 128) * CC;
    const float* scl = scale + g * 512;
    const float* shf = shift + g * 512;
    float* Yg = Y + (size_t)g * 16777216;

    const int lrow   = lane >> 2;        // 0..15 within 16-row wave chunk
    const int lchunk = (lane & 3) * 8;   // bf16 elems
    const int l15 = lane & 15;
    const int kb  = (lane >> 4) * 8;
    const int wm = (w >> 1) * 64, wn = (w & 1) * 64;

    f32x4 acc[4][4];
    f32x4 zz = {0.f, 0.f, 0.f, 0.f};
    #pragma unroll
    for (int i = 0; i < 4; ++i)
        #pragma unroll
        for (int j = 0; j < 4; ++j) acc[i][j] = zz;

    for (int c0 = 0; c0 < CC; c0 += 32) {
        __syncthreads();
        #pragma unroll
        for (int cpy = 0; cpy < 2; ++cpy) {
            int r = w * 32 + cpy * 16 + lrow;
            gld16(Sb + (size_t)r * CC + c0 + lchunk, &Xt[(w * 32 + cpy * 16) * 32]);
        }
        #pragma unroll
        for (int s = 0; s < 3; ++s)
            #pragma unroll
            for (int cpy = 0; cpy < 2; ++cpy) {
                int r = w * 32 + cpy * 16 + lrow;
                gld16(Wb + (size_t)s * CC * CC + (size_t)r * CC + c0 + lchunk,
                      &Wt[s][(w * 32 + cpy * 16) * 32]);
            }
        __syncthreads();

        bf16x8 sf[4];
        #pragma unroll
        for (int i = 0; i < 4; ++i) sf[i] = *(const bf16x8*)&Xt[(wm + i * 16 + l15) * 32 + kb];
        #pragma unroll
        for (int s = 0; s < 3; ++s) {
            bf16x8 wf[4];
            #pragma unroll
            for (int i = 0; i < 4; ++i) wf[i] = *(const bf16x8*)&Wt[s][(wn + i * 16 + l15) * 32 + kb];
            #pragma unroll
            for (int mt = 0; mt < 4; ++mt)
                #pragma unroll
                for (int nt = 0; nt < 4; ++nt)
                    acc[mt][nt] = __builtin_amdgcn_mfma_f32_16x16x32_bf16(sf[mt], wf[nt], acc[mt][nt], 0, 0, 0);
        }
    }

    // epilogue: C/D layout col = lane&15, row = (lane>>4)*4 + reg
    float* Yb = Yg + (size_t)tb * NP * CC;
    #pragma unroll
    for (int nt = 0; nt < 4; ++nt) {
        int o = wtile * 128 + wn + nt * 16 + l15;
        float sc = scl[o], sh = shf[o];
        #pragma unroll
        for (int mt = 0; mt < 4; ++mt) {
            int r0 = stile * 128 + wm + mt * 16 + (lane >> 4) * 4;
            #pragma unroll
            for (int r = 0; r < 4; ++r)
                Yb[(size_t)(r0 + r) * CC + o] = acc[mt][nt][r] * sc + sh;
        }
    }
}

// ---------------- LIF stage 1: q path (3 coupled LIF chains) -> compact bf16 spikes ----------------
// Valid rows only (n < 196). Reads fp32 Yq, writes u16 QS (same padded indexing, different base).
__global__ __launch_bounds__(256) void k_lif_q(const float* __restrict__ Y, u16* __restrict__ QS,
                                               const float* __restrict__ pw_,
                                               const float* __restrict__ pl_,
                                               const float* __restrict__ pb_) {
    size_t idx = (size_t)blockIdx.x * 256 + threadIdx.x;   // over 32*196*512
    int c  = (int)(idx & 511);
    int bn = (int)(idx >> 9);              // b*196 + n
    int b  = bn / 196;
    int n  = bn - b * 196;
    size_t off0 = ((size_t)b * NP + n) * CC + c;
    float pw = log1pf(expf(pw_[0]));
    float pl = log1pf(expf(pl_[0]));
    float pb = pb_[0];
    float von = 0.f, voff = 0.f, vpp = 0.f;
    #pragma unroll
    for (int t = 0; t < TT; ++t) {
        size_t off = off0 + (size_t)t * TSTRIDE;
        float qv = Y[off];
        float h;
        h = von  + ( qv - von ) * 0.5f; bool s1 = (h >= 1.f); von  = s1 ? 0.f : h;
        h = voff + (-qv - voff) * 0.5f; bool s2 = (h >= 1.f); voff = s2 ? 0.f : h;
        float diff = pw * (s1 ? 1.f : 0.f) - pl * (s2 ? 1.f : 0.f) + pb;
        h = vpp  + (diff - vpp) * 0.5f; bool sp = (h >= 1.f); vpp  = sp ? 0.f : h;
        QS[off] = sp ? 0x3F80 : 0;
    }
}

// ---------------- LIF stage 2: k and v plain LIF -> compact bf16 spikes ----------------
__global__ __launch_bounds__(256) void k_lif_kv(const float* __restrict__ Yk, const float* __restrict__ Yv,
                                                u16* __restrict__ KS, u16* __restrict__ VS) {
    size_t idx = (size_t)blockIdx.x * 256 + threadIdx.x;   // over 32*196*512
    int c  = (int)(idx & 511);
    int bn = (int)(idx >> 9);
    int b  = bn / 196;
    int n  = bn - b * 196;
    size_t off0 = ((size_t)b * NP + n) * CC + c;
    float vk = 0.f, vv = 0.f;
    #pragma unroll
    for (int t = 0; t < TT; ++t) {
        size_t off = off0 + (size_t)t * TSTRIDE;
        float kv = Yk[off], xv = Yv[off];
        float h;
        h = vk + (kv - vk) * 0.5f; bool sk = (h >= 1.f); vk = sk ? 0.f : h;
        h = vv + (xv - vv) * 0.5f; bool sv = (h >= 1.f); vv = sv ? 0.f : h;
        KS[off] = sk ? 0x3F80 : 0;
        VS[off] = sv ? 0x3F80 : 0;
    }
}

// ---------------- MFMA attention per (tb,h): kv = K^T V ; O = 0.125 * Q_pp kv -> bf16 [tb][n][C] ----------------
// Inputs: compact bf16 spike tensors [tb][n(256)][C] (rows n>=196 are garbage, masked out).
__global__ __launch_bounds__(256) void k_attn(const u16* __restrict__ Q, const u16* __restrict__ K,
                                              const u16* __restrict__ V, u16* __restrict__ OS) {
    __shared__ __align__(16) u16 sm[19584];   // max(2*64*136, 208*72 + 64*72) u16 = 39168 B
    u16* Kt  = sm;            // phase A: [64 d][136]
    u16* Vt  = sm + 8704;     // phase A: [64 e][136]
    u16* Qs  = sm;            // phase B: [208 n][72]
    u16* kvT = sm + 14976;    // phase B: [64 e][72]

    const int tid = threadIdx.x;
    const int tb  = blockIdx.x >> 3;
    const int h   = blockIdx.x & 7;
    const size_t gb = (size_t)tb * (NP * CC) + (size_t)h * HD;

    const int srow = tid >> 2;            // 0..63 staging row
    const int sdq  = (tid & 3) * 16;      // 0,16,32,48

    const int lane = tid & 63;
    const int w    = tid >> 6;
    const int l15  = lane & 15;
    const int kb8  = (lane >> 4) * 8;
    const int quad = (lane >> 4) * 4;
    const int dh = (w >> 1) * 32, eh = (w & 1) * 32;

    f32x4 accA[2][2];
    f32x4 zz = {0.f, 0.f, 0.f, 0.f};
    #pragma unroll
    for (int i = 0; i < 2; ++i)
        #pragma unroll
        for (int j = 0; j < 2; ++j) accA[i][j] = zz;

    const uint4 z4 = make_uint4(0, 0, 0, 0);

    // ---- phase A over 2 n-chunks of 128
    #pragma unroll
    for (int ch = 0; ch < 2; ++ch) {
        if (ch) __syncthreads();
        #pragma unroll
        for (int c = 0; c < 2; ++c) {
            int n  = ch * 128 + c * 64 + srow;
            int nl = c * 64 + srow;
            bool valid = n < NN;
            const u16* kr = K + gb + (size_t)n * CC + sdq;
            const u16* vr = V + gb + (size_t)n * CC + sdq;
            uint4 ka  = valid ? *(const uint4*)kr : z4;
            uint4 kb2 = valid ? *(const uint4*)(kr + 8) : z4;
            uint4 va  = valid ? *(const uint4*)vr : z4;
            uint4 vb2 = valid ? *(const uint4*)(vr + 8) : z4;
            u32 kwv[8] = {ka.x, ka.y, ka.z, ka.w, kb2.x, kb2.y, kb2.z, kb2.w};
            u32 vwv[8] = {va.x, va.y, va.z, va.w, vb2.x, vb2.y, vb2.z, vb2.w};
            #pragma unroll
            for (int i = 0; i < 8; ++i) {
                Kt[(sdq + 2 * i) * 136 + nl]     = (u16)(kwv[i] & 0xFFFF);
                Kt[(sdq + 2 * i + 1) * 136 + nl] = (u16)(kwv[i] >> 16);
                Vt[(sdq + 2 * i) * 136 + nl]     = (u16)(vwv[i] & 0xFFFF);
                Vt[(sdq + 2 * i + 1) * 136 + nl] = (u16)(vwv[i] >> 16);
            }
        }
        __syncthreads();
        #pragma unroll
        for (int k0 = 0; k0 < 128; k0 += 32) {
            bf16x8 af[2], bv[2];
            #pragma unroll
            for (int i = 0; i < 2; ++i) {
                af[i] = *(const bf16x8*)&Kt[(dh + i * 16 + l15) * 136 + k0 + kb8];
                bv[i] = *(const bf16x8*)&Vt[(eh + i * 16 + l15) * 136 + k0 + kb8];
            }
            #pragma unroll
            for (int i = 0; i < 2; ++i)
                #pragma unroll
                for (int j = 0; j < 2; ++j)
                    accA[i][j] = __builtin_amdgcn_mfma_f32_16x16x32_bf16(af[i], bv[j], accA[i][j], 0, 0, 0);
        }
    }
    __syncthreads();   // all waves done with Kt/Vt before overwrite

    // ---- write kv^T (bf16, exact: integers <= 196) and stage Q
    #pragma unroll
    for (int i = 0; i < 2; ++i)
        #pragma unroll
        for (int j = 0; j < 2; ++j)
            #pragma unroll
            for (int r = 0; r < 4; ++r) {
                int e = eh + j * 16 + l15;
                int d = dh + i * 16 + quad + r;
                kvT[e * 72 + d] = f2bf(accA[i][j][r]);
            }
    #pragma unroll
    for (int p = 0; p < 4; ++p) {
        int n = p * 64 + srow;
        if (n < 208) {
            const u16* qr = Q + gb + (size_t)n * CC + sdq;
            uint4 qa  = *(const uint4*)qr;
            uint4 qb2 = *(const uint4*)(qr + 8);
            u32 qwv[8] = {qa.x, qa.y, qa.z, qa.w, qb2.x, qb2.y, qb2.z, qb2.w};
            #pragma unroll
            for (int i = 0; i < 8; ++i) {
                Qs[n * 72 + sdq + 2 * i]     = (u16)(qwv[i] & 0xFFFF);
                Qs[n * 72 + sdq + 2 * i + 1] = (u16)(qwv[i] >> 16);
            }
        }
    }
    __syncthreads();

    // ---- phase B: wave w owns e-tile [w*16, w*16+16)
    bf16x8 bq0 = *(const bf16x8*)&kvT[(w * 16 + l15) * 72 + 0  + kb8];
    bf16x8 bq1 = *(const bf16x8*)&kvT[(w * 16 + l15) * 72 + 32 + kb8];
    u16* ob = OS + (size_t)tb * (NP * CC) + (size_t)h * HD + w * 16 + l15;
    #pragma unroll
    for (int nt = 0; nt < 13; ++nt) {
        f32x4 acc = zz;
        bf16x8 a0 = *(const bf16x8*)&Qs[(nt * 16 + l15) * 72 + 0  + kb8];
        bf16x8 a1 = *(const bf16x8*)&Qs[(nt * 16 + l15) * 72 + 32 + kb8];
        acc = __builtin_amdgcn_mfma_f32_16x16x32_bf16(a0, bq0, acc, 0, 0, 0);
        acc = __builtin_amdgcn_mfma_f32_16x16x32_bf16(a1, bq1, acc, 0, 0, 0);
        #pragma unroll
        for (int r = 0; r < 4; ++r) {
            int n = nt * 16 + quad + r;
            if (n < NN) ob[(size_t)n * CC] = f2bf(acc[r] * 0.125f);
        }
    }
}

// ---------------- attn LIF (vth=0.5), valid rows only, in place on bf16 ----------------
__global__ __launch_bounds__(256) void k_attn_lif(u16* __restrict__ OS) {
    size_t idx = (size_t)blockIdx.x * 256 + threadIdx.x;   // over 32*196*512
    int c  = (int)(idx & 511);
    int bn = (int)(idx >> 9);
    int b  = bn / 196;
    int n  = bn - b * 196;
    size_t off0 = ((size_t)b * NP + n) * CC + c;
    float v = 0.f;
    #pragma unroll
    for (int t = 0; t < TT; ++t) {
        size_t off = off0 + (size_t)t * TSTRIDE;
        float xv = bf2f(OS[off]);
        float h = v + (xv - v) * 0.5f;
        bool s = (h >= 0.5f);
        v = s ? 0.f : h;
        OS[off] = s ? 0x3F80 : 0;
    }
}

// ---------------- final projection GEMM: out[tb][o][n<196] = BN(W_p x spikes^T) ----------------
// Pad spike rows (n>=196) may hold garbage; their products only reach discarded n>=196 outputs.
__global__ __launch_bounds__(256) void k_gemm_proj(const u16* __restrict__ S, const u16* __restrict__ W3,
                                                   const float* __restrict__ scale, const float* __restrict__ shift,
                                                   float* __restrict__ Y) {
    __shared__ __align__(16) u16 Xt[128 * 32];
    __shared__ __align__(16) u16 Wt[3][128 * 32];
    const int tid  = threadIdx.x;
    const int lane = tid & 63;
    const int w    = tid >> 6;
    const int wtile = blockIdx.x;   // 0..3 (o)
    const int stile = blockIdx.y;   // 0..1 (n)
    const int tb    = blockIdx.z;
    const u16* Sb = S + (size_t)tb * NP * CC + (size_t)(stile * 128) * CC;
    const u16* Wb = W3 + (size_t)(wtile * 128) * CC;

    const int lrow   = lane >> 2;
    const int lchunk = (lane & 3) * 8;
    const int l15 = lane & 15;
    const int kb  = (lane >> 4) * 8;
    const int wm = (w >> 1) * 64, wn = (w & 1) * 64;

    f32x4 acc[4][4];
    f32x4 zz = {0.f, 0.f, 0.f, 0.f};
    #pragma unroll
    for (int i = 0; i < 4; ++i)
        #pragma unroll
        for (int j = 0; j < 4; ++j) acc[i][j] = zz;

    for (int c0 = 0; c0 < CC; c0 += 32) {
        __syncthreads();
        #pragma unroll
        for (int cpy = 0; cpy < 2; ++cpy) {
            int r = w * 32 + cpy * 16 + lrow;
            gld16(Sb + (size_t)r * CC + c0 + lchunk, &Xt[(w * 32 + cpy * 16) * 32]);
        }
        #pragma unroll
        for (int s = 0; s < 3; ++s)
            #pragma unroll
            for (int cpy = 0; cpy < 2; ++cpy) {
                int r = w * 32 + cpy * 16 + lrow;
                gld16(Wb + (size_t)s * CC * CC + (size_t)r * CC + c0 + lchunk,
                      &Wt[s][(w * 32 + cpy * 16) * 32]);
            }
        __syncthreads();

        bf16x8 sf[4];
        #pragma unroll
        for (int i = 0; i < 4; ++i) sf[i] = *(const bf16x8*)&Xt[(wn + i * 16 + l15) * 32 + kb];
        #pragma unroll
        for (int s = 0; s < 3; ++s) {
            bf16x8 wf[4];
            #pragma unroll
            for (int i = 0; i < 4; ++i) wf[i] = *(const bf16x8*)&Wt[s][(wm + i * 16 + l15) * 32 + kb];
            #pragma unroll
            for (int mt = 0; mt < 4; ++mt)
                #pragma unroll
                for (int nt = 0; nt < 4; ++nt)
                    acc[mt][nt] = __builtin_amdgcn_mfma_f32_16x16x32_bf16(wf[mt], sf[nt], acc[mt][nt], 0, 0, 0);
        }
    }

    float* Yb = Y + (size_t)tb * CC * NN;
    #pragma unroll
    for (int mt = 0; mt < 4; ++mt) {
        int o0 = wtile * 128 + wm + mt * 16 + (lane >> 4) * 4;
        #pragma unroll
        for (int nt = 0; nt < 4; ++nt) {
            int n = stile * 128 + wn + nt * 16 + l15;
            if (n < NN) {
                #pragma unroll
                for (int r = 0; r < 4; ++r)
                    Yb[(size_t)(o0 + r) * NN + n] = acc[mt][nt][r] * scale[o0 + r] + shift[o0 + r];
            }
        }
    }
}

extern "C" void kernel_launch(void* const* d_in, const int* in_sizes, int n_in,
                              void* d_out, int out_size, void* d_ws, size_t ws_size,
                              hipStream_t stream) {
    const float* x    = (const float*)d_in[0];
    const float* q_cw = (const float*)d_in[1];
    const float* q_cb = (const float*)d_in[2];
    const float* q_bg = (const float*)d_in[3];
    const float* q_bb = (const float*)d_in[4];
    const float* q_bm = (const float*)d_in[5];
    const float* q_bv = (const float*)d_in[6];
    const float* k_cw = (const float*)d_in[7];
    const float* k_cb = (const float*)d_in[8];
    const float* k_bg = (const float*)d_in[9];
    const float* k_bb = (const float*)d_in[10];
    const float* k_bm = (const float*)d_in[11];
    const float* k_bv = (const float*)d_in[12];
    const float* v_cw = (const float*)d_in[13];
    const float* v_cb = (const float*)d_in[14];
    const float* v_bg = (const float*)d_in[15];
    const float* v_bb = (const float*)d_in[16];
    const float* v_bm = (const float*)d_in[17];
    const float* v_bv = (const float*)d_in[18];
    const float* p_cw = (const float*)d_in[19];
    const float* p_cb = (const float*)d_in[20];
    const float* p_bg = (const float*)d_in[21];
    const float* p_bb = (const float*)d_in[22];
    const float* p_bm = (const float*)d_in[23];
    const float* p_bv = (const float*)d_in[24];
    const float* pshw = (const float*)d_in[25];
    const float* pllw = (const float*)d_in[26];
    const float* ppb  = (const float*)d_in[27];
    float* out = (float*)d_out;

    // ws map (242 MB proven budget):
    //   [0,32)    XS head spikes; reused as QS after gemm_qkv
    //   [32,96)   Yq fp32; reused as KS[32,64)+VS[64,96) after k_lif_q consumed Yq
    //   [96,160)  Yk fp32; [96,128) reused as OS (attn output) after k_lif_kv
    //   [160,224) Yv fp32
    //   [224,..)  W3 (6 MB) + SS/SH
    if (ws_size < (size_t)242 * 1024 * 1024) return;
    char* W = (char*)d_ws;
    u16*   XS = (u16*)W;
    u16*   QS = (u16*)W;
    u16*   KS = (u16*)(W + ((size_t)32 << 20));
    u16*   VS = (u16*)(W + ((size_t)64 << 20));
    u16*   OS = (u16*)(W + ((size_t)96 << 20));
    float* Yq = (float*)(W + ((size_t)32 << 20));
    float* Yk = (float*)(W + ((size_t)96 << 20));
    float* Yv = (float*)(W + ((size_t)160 << 20));
    u16*   W3 = (u16*)(W + ((size_t)224 << 20));
    float* SS = (float*)(W + ((size_t)224 << 20) + 6291456);  // scale[4][512]
    float* SH = SS + 2048;                                     // shift[4][512]

    k_prep_w<<<4096, 256, 0, stream>>>(q_cw, k_cw, v_cw, p_cw, W3);
    k_prep_bn4<<<8, 256, 0, stream>>>(q_cb, q_bg, q_bb, q_bm, q_bv,
                                      k_cb, k_bg, k_bb, k_bm, k_bv,
                                      v_cb, v_bg, v_bb, v_bm, v_bv,
                                      p_cb, p_bg, p_bb, p_bm, p_bv, SS, SH);

    k_head_lif<<<dim3(4, 32, 2), 256, 0, stream>>>(x, XS);

    // merged Q/K/V projection: blockIdx.x = g*4 + wtile; Y offsets g*64MB (Yq,Yk,Yv contiguous)
    k_gemm_qkv<<<dim3(12, 2, TBB), 256, 0, stream>>>(XS, W3, SS, SH, Yq);

    const int validBlocks = (int)(NVALID / 256);   // 12544
    // stage 1: q LIF -> QS (overwrites XS, dead). stage 2: k/v LIF -> KS/VS (overwrite Yq, dead).
    k_lif_q<<<validBlocks, 256, 0, stream>>>(Yq, QS, pshw, pllw, ppb);
    k_lif_kv<<<validBlocks, 256, 0, stream>>>(Yk, Yv, KS, VS);

    k_attn<<<TBB * NHH, 256, 0, stream>>>(QS, KS, VS, OS);   // OS overwrites Yk (dead)
    k_attn_lif<<<validBlocks, 256, 0, stream>>>(OS);

    k_gemm_proj<<<dim3(4, 2, TBB), 256, 0, stream>>>(OS, W3 + 3 * 786432, SS + 1536, SH + 1536, out);
}

// Round 7
// 423.814 us; speedup vs baseline: 1.2457x; 1.1039x over previous
//
#include <hip/hip_runtime.h>
#include <hip/hip_bf16.h>
#include <math.h>

typedef unsigned short u16;
typedef unsigned int   u32;

#define CC 512
#define NN 196
#define TT 4
#define BB 32
#define TBB 128
#define NHH 8
#define HD 64

// compact-row layout: row = tb*196 + n, M = 128*196 = 25088 rows
#define MROWS   25088
#define ROWS_T  6272                      // rows per t-slice (32*196)
#define CSTRIDE ((size_t)ROWS_T * CC)     // elems per t-slice = 3,211,264

typedef __attribute__((ext_vector_type(8))) short bf16x8;
typedef __attribute__((ext_vector_type(4))) float f32x4;

__device__ __forceinline__ u16 f2bf(float f) {
    __hip_bfloat16 h = __float2bfloat16(f);
    return *(u16*)&h;
}
__device__ __forceinline__ float bf2f(u16 u) {
    u32 ui = ((u32)u) << 16;
    return __uint_as_float(ui);
}
__device__ __forceinline__ u32 pk2(u16 a, u16 b) { return (u32)a | ((u32)b << 16); }

// async 16B/lane global->LDS; lds base must be wave-uniform
__device__ __forceinline__ void gld16(const void* g, void* l) {
    __builtin_amdgcn_global_load_lds(
        (const __attribute__((address_space(1))) void*)g,
        (__attribute__((address_space(3))) void*)l, 16, 0, 0);
}

// ---------------- prep: split fp32 weights into 3 exact bf16 planes ----------------
__global__ __launch_bounds__(256) void k_prep_w(const float* __restrict__ qw, const float* __restrict__ kw,
                                                const float* __restrict__ vw, const float* __restrict__ pw,
                                                u16* __restrict__ W3) {
    size_t idx = (size_t)blockIdx.x * 256 + threadIdx.x;   // 4 * 262144
    int g = (int)(idx >> 18);
    size_t rem = idx & 262143;
    const float* Ws = (g == 0) ? qw : (g == 1) ? kw : (g == 2) ? vw : pw;
    float w  = Ws[rem];
    u16 u0 = f2bf(w);      float b0 = bf2f(u0);
    float r1 = w - b0;
    u16 u1 = f2bf(r1);     float b1 = bf2f(u1);
    float r2 = r1 - b1;
    u16 u2 = f2bf(r2);
    size_t base = (size_t)g * 786432 + rem;
    W3[base] = u0; W3[base + 262144] = u1; W3[base + 524288] = u2;
}

// all 4 BN param groups in one launch
__global__ __launch_bounds__(256) void k_prep_bn4(
    const float* __restrict__ cb0, const float* __restrict__ bg0, const float* __restrict__ bb0,
    const float* __restrict__ bm0, const float* __restrict__ bv0,
    const float* __restrict__ cb1, const float* __restrict__ bg1, const float* __restrict__ bb1,
    const float* __restrict__ bm1, const float* __restrict__ bv1,
    const float* __restrict__ cb2, const float* __restrict__ bg2, const float* __restrict__ bb2,
    const float* __restrict__ bm2, const float* __restrict__ bv2,
    const float* __restrict__ cb3, const float* __restrict__ bg3, const float* __restrict__ bb3,
    const float* __restrict__ bm3, const float* __restrict__ bv3,
    float* __restrict__ SS, float* __restrict__ SH) {
    int idx = blockIdx.x * 256 + threadIdx.x;
    int g = idx >> 9, o = idx & 511;
    const float* cb = g == 0 ? cb0 : g == 1 ? cb1 : g == 2 ? cb2 : cb3;
    const float* bg = g == 0 ? bg0 : g == 1 ? bg1 : g == 2 ? bg2 : bg3;
    const float* bb = g == 0 ? bb0 : g == 1 ? bb1 : g == 2 ? bb2 : bb3;
    const float* bm = g == 0 ? bm0 : g == 1 ? bm1 : g == 2 ? bm2 : bm3;
    const float* bv = g == 0 ? bv0 : g == 1 ? bv1 : g == 2 ? bv2 : bv3;
    float inv = bg[o] / sqrtf(bv[o] + 1e-5f);
    SS[g * 512 + o] = inv;
    SH[g * 512 + o] = (cb[o] - bm[o]) * inv + bb[o];
}

// ---------------- head LIF + transpose: x[t][b][C][196] -> XS[tb*196+n][C] bf16 spikes (compact) ----------------
__global__ __launch_bounds__(256) void k_head_lif(const float* __restrict__ x, u16* __restrict__ XS) {
    __shared__ float T[64][65];
    const int tid = threadIdx.x;
    const int n0 = blockIdx.x * 64;       // 0..3 * 64
    const int b  = blockIdx.y;            // 0..31
    const int ch = blockIdx.z;            // 0..1
    const int n_l = tid & 63;
    const int c_r0 = tid >> 6;            // 0..3
    const int n_r = tid >> 2;             // 0..63
    const int cq  = (tid & 3) * 16;
    const bool wv = (n0 + n_r) < NN;

    for (int cc = 0; cc < 4; ++cc) {
        const int c_base = ch * 256 + cc * 64;
        float v[16];
        #pragma unroll
        for (int j = 0; j < 16; ++j) v[j] = 0.f;
        for (int t = 0; t < TT; ++t) {
            const size_t xb = ((size_t)(t * BB + b) * CC + c_base) * NN;
            float s[16];
            #pragma unroll
            for (int j = 0; j < 16; ++j) {
                int c_l = c_r0 + 4 * j;
                float xv = (n0 + n_l < NN) ? x[xb + (size_t)c_l * NN + n0 + n_l] : 0.f;
                float h = v[j] + (xv - v[j]) * 0.5f;
                s[j] = (h >= 1.f) ? 1.f : 0.f;
                v[j] = (h >= 1.f) ? 0.f : h;
            }
            __syncthreads();
            #pragma unroll
            for (int j = 0; j < 16; ++j) T[c_r0 + 4 * j][n_l] = s[j];
            __syncthreads();
            if (wv) {
                const size_t ob = ((size_t)(t * BB + b) * NN + n0 + n_r) * CC + c_base + cq;
                u16 u[16];
                #pragma unroll
                for (int m = 0; m < 16; ++m) u[m] = (T[cq + m][n_r] != 0.f) ? 0x3F80 : 0;
                uint4 q0 = make_uint4(pk2(u[0],u[1]),  pk2(u[2],u[3]),  pk2(u[4],u[5]),  pk2(u[6],u[7]));
                uint4 q1 = make_uint4(pk2(u[8],u[9]),  pk2(u[10],u[11]),pk2(u[12],u[13]),pk2(u[14],u[15]));
                *(uint4*)(XS + ob)     = q0;
                *(uint4*)(XS + ob + 8) = q1;
            }
            __syncthreads();
        }
    }
}

// ---------------- merged QKV MFMA GEMM over compact rows, 3-split bf16 weights ----------------
// blockIdx.x = g*4 + wtile; blockIdx.y = ntile (196 tiles of 128 rows, exact)
// D[m=row][n'=o] -> Y fp32 [row][512] at base + g*YSTRIDE_F
#define YSTRIDE_F 13631488   // 52MB / 4
__global__ __launch_bounds__(256) void k_gemm_qkv(const u16* __restrict__ S, const u16* __restrict__ W3,
                                                  const float* __restrict__ scale, const float* __restrict__ shift,
                                                  float* __restrict__ Y) {
    __shared__ __align__(16) u16 Xt[128 * 32];
    __shared__ __align__(16) u16 Wt[3][128 * 32];
    const int tid  = threadIdx.x;
    const int lane = tid & 63;
    const int w    = tid >> 6;
    const int g     = blockIdx.x >> 2;
    const int wtile = blockIdx.x & 3;
    const int ntile = blockIdx.y;   // 0..195
    const u16* Sb = S + (size_t)ntile * 128 * CC;
    const u16* Wb = W3 + (size_t)g * 786432 + (size_t)(wtile * 128) * CC;
    const float* scl = scale + g * 512;
    const float* shf = shift + g * 512;
    float* Yg = Y + (size_t)g * YSTRIDE_F;

    const int lrow   = lane >> 2;        // 0..15
    const int lchunk = (lane & 3) * 8;   // bf16 elems
    const int l15 = lane & 15;
    const int kb  = (lane >> 4) * 8;
    const int wm = (w >> 1) * 64, wn = (w & 1) * 64;

    f32x4 acc[4][4];
    f32x4 zz = {0.f, 0.f, 0.f, 0.f};
    #pragma unroll
    for (int i = 0; i < 4; ++i)
        #pragma unroll
        for (int j = 0; j < 4; ++j) acc[i][j] = zz;

    for (int c0 = 0; c0 < CC; c0 += 32) {
        __syncthreads();
        #pragma unroll
        for (int cpy = 0; cpy < 2; ++cpy) {
            int r = w * 32 + cpy * 16 + lrow;
            gld16(Sb + (size_t)r * CC + c0 + lchunk, &Xt[(w * 32 + cpy * 16) * 32]);
        }
        #pragma unroll
        for (int s = 0; s < 3; ++s)
            #pragma unroll
            for (int cpy = 0; cpy < 2; ++cpy) {
                int r = w * 32 + cpy * 16 + lrow;
                gld16(Wb + (size_t)s * CC * CC + (size_t)r * CC + c0 + lchunk,
                      &Wt[s][(w * 32 + cpy * 16) * 32]);
            }
        __syncthreads();

        bf16x8 sf[4];
        #pragma unroll
        for (int i = 0; i < 4; ++i) sf[i] = *(const bf16x8*)&Xt[(wm + i * 16 + l15) * 32 + kb];
        #pragma unroll
        for (int s = 0; s < 3; ++s) {
            bf16x8 wf[4];
            #pragma unroll
            for (int i = 0; i < 4; ++i) wf[i] = *(const bf16x8*)&Wt[s][(wn + i * 16 + l15) * 32 + kb];
            #pragma unroll
            for (int mt = 0; mt < 4; ++mt)
                #pragma unroll
                for (int nt = 0; nt < 4; ++nt)
                    acc[mt][nt] = __builtin_amdgcn_mfma_f32_16x16x32_bf16(sf[mt], wf[nt], acc[mt][nt], 0, 0, 0);
        }
    }

    // epilogue: C/D layout col = lane&15, row = (lane>>4)*4 + reg
    #pragma unroll
    for (int nt = 0; nt < 4; ++nt) {
        int o = wtile * 128 + wn + nt * 16 + l15;
        float sc = scl[o], sh = shf[o];
        #pragma unroll
        for (int mt = 0; mt < 4; ++mt) {
            int r0 = ntile * 128 + wm + mt * 16 + (lane >> 4) * 4;
            #pragma unroll
            for (int r = 0; r < 4; ++r)
                Yg[(size_t)(r0 + r) * CC + o] = acc[mt][nt][r] * sc + sh;
        }
    }
}

// ---------------- merged LIF: q (3 chains) + k + v -> compact bf16 spikes ----------------
__global__ __launch_bounds__(256) void k_lif_all(const float* __restrict__ Yq, const float* __restrict__ Yk,
                                                 const float* __restrict__ Yv, u16* __restrict__ QS,
                                                 u16* __restrict__ KS, u16* __restrict__ VS,
                                                 const float* __restrict__ pw_,
                                                 const float* __restrict__ pl_,
                                                 const float* __restrict__ pb_) {
    size_t idx = (size_t)blockIdx.x * 256 + threadIdx.x;   // flat over one t-slice (3,211,264)
    float pw = log1pf(expf(pw_[0]));
    float pl = log1pf(expf(pl_[0]));
    float pb = pb_[0];
    float von = 0.f, voff = 0.f, vpp = 0.f, vk = 0.f, vv = 0.f;
    #pragma unroll
    for (int t = 0; t < TT; ++t) {
        size_t off = idx + (size_t)t * CSTRIDE;
        float qv = Yq[off], kv = Yk[off], xv = Yv[off];
        float h;
        h = von  + ( qv - von ) * 0.5f; bool s1 = (h >= 1.f); von  = s1 ? 0.f : h;
        h = voff + (-qv - voff) * 0.5f; bool s2 = (h >= 1.f); voff = s2 ? 0.f : h;
        float diff = pw * (s1 ? 1.f : 0.f) - pl * (s2 ? 1.f : 0.f) + pb;
        h = vpp  + (diff - vpp) * 0.5f; bool sp = (h >= 1.f); vpp  = sp ? 0.f : h;
        h = vk   + ( kv - vk  ) * 0.5f; bool sk = (h >= 1.f); vk   = sk ? 0.f : h;
        h = vv   + ( xv - vv  ) * 0.5f; bool sv = (h >= 1.f); vv   = sv ? 0.f : h;
        QS[off] = sp ? 0x3F80 : 0;
        KS[off] = sk ? 0x3F80 : 0;
        VS[off] = sv ? 0x3F80 : 0;
    }
}

// ---------------- MFMA attention per (tb,h): kv = K^T V ; O = 0.125 * Q_pp kv -> bf16 compact ----------------
__global__ __launch_bounds__(256) void k_attn(const u16* __restrict__ Q, const u16* __restrict__ K,
                                              const u16* __restrict__ V, u16* __restrict__ OS) {
    __shared__ __align__(16) u16 sm[19584];   // max(2*64*136, 208*72 + 64*72) u16 = 39168 B
    u16* Kt  = sm;            // phase A: [64 d][136]
    u16* Vt  = sm + 8704;     // phase A: [64 e][136]
    u16* Qs  = sm;            // phase B: [208 n][72]
    u16* kvT = sm + 14976;    // phase B: [64 e][72]

    const int tid = threadIdx.x;
    const int tb  = blockIdx.x >> 3;
    const int h   = blockIdx.x & 7;
    const size_t gb = (size_t)tb * NN * CC + (size_t)h * HD;

    const int srow = tid >> 2;            // 0..63 staging row
    const int sdq  = (tid & 3) * 16;      // 0,16,32,48

    const int lane = tid & 63;
    const int w    = tid >> 6;
    const int l15  = lane & 15;
    const int kb8  = (lane >> 4) * 8;
    const int quad = (lane >> 4) * 4;
    const int dh = (w >> 1) * 32, eh = (w & 1) * 32;

    f32x4 accA[2][2];
    f32x4 zz = {0.f, 0.f, 0.f, 0.f};
    #pragma unroll
    for (int i = 0; i < 2; ++i)
        #pragma unroll
        for (int j = 0; j < 2; ++j) accA[i][j] = zz;

    const uint4 z4 = make_uint4(0, 0, 0, 0);

    // ---- phase A over 2 n-chunks of 128
    #pragma unroll
    for (int ch = 0; ch < 2; ++ch) {
        if (ch) __syncthreads();
        #pragma unroll
        for (int c = 0; c < 2; ++c) {
            int n  = ch * 128 + c * 64 + srow;
            int nl = c * 64 + srow;
            bool valid = n < NN;
            const u16* kr = K + gb + (size_t)n * CC + sdq;
            const u16* vr = V + gb + (size_t)n * CC + sdq;
            uint4 ka  = valid ? *(const uint4*)kr : z4;
            uint4 kb2 = valid ? *(const uint4*)(kr + 8) : z4;
            uint4 va  = valid ? *(const uint4*)vr : z4;
            uint4 vb2 = valid ? *(const uint4*)(vr + 8) : z4;
            u32 kwv[8] = {ka.x, ka.y, ka.z, ka.w, kb2.x, kb2.y, kb2.z, kb2.w};
            u32 vwv[8] = {va.x, va.y, va.z, va.w, vb2.x, vb2.y, vb2.z, vb2.w};
            #pragma unroll
            for (int i = 0; i < 8; ++i) {
                Kt[(sdq + 2 * i) * 136 + nl]     = (u16)(kwv[i] & 0xFFFF);
                Kt[(sdq + 2 * i + 1) * 136 + nl] = (u16)(kwv[i] >> 16);
                Vt[(sdq + 2 * i) * 136 + nl]     = (u16)(vwv[i] & 0xFFFF);
                Vt[(sdq + 2 * i + 1) * 136 + nl] = (u16)(vwv[i] >> 16);
            }
        }
        __syncthreads();
        #pragma unroll
        for (int k0 = 0; k0 < 128; k0 += 32) {
            bf16x8 af[2], bv[2];
            #pragma unroll
            for (int i = 0; i < 2; ++i) {
                af[i] = *(const bf16x8*)&Kt[(dh + i * 16 + l15) * 136 + k0 + kb8];
                bv[i] = *(const bf16x8*)&Vt[(eh + i * 16 + l15) * 136 + k0 + kb8];
            }
            #pragma unroll
            for (int i = 0; i < 2; ++i)
                #pragma unroll
                for (int j = 0; j < 2; ++j)
                    accA[i][j] = __builtin_amdgcn_mfma_f32_16x16x32_bf16(af[i], bv[j], accA[i][j], 0, 0, 0);
        }
    }
    __syncthreads();   // all waves done with Kt/Vt before overwrite

    // ---- write kv^T (bf16, exact: integers <= 196) and stage Q
    #pragma unroll
    for (int i = 0; i < 2; ++i)
        #pragma unroll
        for (int j = 0; j < 2; ++j)
            #pragma unroll
            for (int r = 0; r < 4; ++r) {
                int e = eh + j * 16 + l15;
                int d = dh + i * 16 + quad + r;
                kvT[e * 72 + d] = f2bf(accA[i][j][r]);
            }
    #pragma unroll
    for (int p = 0; p < 4; ++p) {
        int n = p * 64 + srow;
        if (n < 208) {
            if (n < NN) {
                const u16* qr = Q + gb + (size_t)n * CC + sdq;
                uint4 qa  = *(const uint4*)qr;
                uint4 qb2 = *(const uint4*)(qr + 8);
                u32 qwv[8] = {qa.x, qa.y, qa.z, qa.w, qb2.x, qb2.y, qb2.z, qb2.w};
                #pragma unroll
                for (int i = 0; i < 8; ++i) {
                    Qs[n * 72 + sdq + 2 * i]     = (u16)(qwv[i] & 0xFFFF);
                    Qs[n * 72 + sdq + 2 * i + 1] = (u16)(qwv[i] >> 16);
                }
            } else {
                #pragma unroll
                for (int i = 0; i < 16; ++i) Qs[n * 72 + sdq + i] = 0;
            }
        }
    }
    __syncthreads();

    // ---- phase B: wave w owns e-tile [w*16, w*16+16)
    bf16x8 bq0 = *(const bf16x8*)&kvT[(w * 16 + l15) * 72 + 0  + kb8];
    bf16x8 bq1 = *(const bf16x8*)&kvT[(w * 16 + l15) * 72 + 32 + kb8];
    u16* ob = OS + (size_t)tb * NN * CC + (size_t)h * HD + w * 16 + l15;
    #pragma unroll
    for (int nt = 0; nt < 13; ++nt) {
        f32x4 acc = zz;
        bf16x8 a0 = *(const bf16x8*)&Qs[(nt * 16 + l15) * 72 + 0  + kb8];
        bf16x8 a1 = *(const bf16x8*)&Qs[(nt * 16 + l15) * 72 + 32 + kb8];
        acc = __builtin_amdgcn_mfma_f32_16x16x32_bf16(a0, bq0, acc, 0, 0, 0);
        acc = __builtin_amdgcn_mfma_f32_16x16x32_bf16(a1, bq1, acc, 0, 0, 0);
        #pragma unroll
        for (int r = 0; r < 4; ++r) {
            int n = nt * 16 + quad + r;
            if (n < NN) ob[(size_t)n * CC] = f2bf(acc[r] * 0.125f);
        }
    }
}

// ---------------- attn LIF (vth=0.5), compact flat, in place on bf16 ----------------
__global__ __launch_bounds__(256) void k_attn_lif(u16* __restrict__ OS) {
    size_t idx = (size_t)blockIdx.x * 256 + threadIdx.x;   // flat over one t-slice
    float v = 0.f;
    #pragma unroll
    for (int t = 0; t < TT; ++t) {
        size_t off = idx + (size_t)t * CSTRIDE;
        float xv = bf2f(OS[off]);
        float h = v + (xv - v) * 0.5f;
        bool s = (h >= 0.5f);
        v = s ? 0.f : h;
        OS[off] = s ? 0x3F80 : 0;
    }
}

// ---------------- final projection GEMM: out[tb][o][n] = BN(W_p x spikes^T), compact rows ----------------
__global__ __launch_bounds__(256) void k_gemm_proj(const u16* __restrict__ S, const u16* __restrict__ W3,
                                                   const float* __restrict__ scale, const float* __restrict__ shift,
                                                   float* __restrict__ Y) {
    __shared__ __align__(16) u16 Xt[128 * 32];
    __shared__ __align__(16) u16 Wt[3][128 * 32];
    const int tid  = threadIdx.x;
    const int lane = tid & 63;
    const int w    = tid >> 6;
    const int wtile = blockIdx.x;   // 0..3 (o)
    const int ntile = blockIdx.y;   // 0..195 (row tiles, exact)
    const u16* Sb = S + (size_t)ntile * 128 * CC;
    const u16* Wb = W3 + (size_t)(wtile * 128) * CC;

    const int lrow   = lane >> 2;
    const int lchunk = (lane & 3) * 8;
    const int l15 = lane & 15;
    const int kb  = (lane >> 4) * 8;
    const int wm = (w >> 1) * 64, wn = (w & 1) * 64;

    // a 128-row tile crosses at most one tb boundary
    const int tb0 = (ntile * 128) / NN;
    const int bnd = (tb0 + 1) * NN;

    f32x4 acc[4][4];
    f32x4 zz = {0.f, 0.f, 0.f, 0.f};
    #pragma unroll
    for (int i = 0; i < 4; ++i)
        #pragma unroll
        for (int j = 0; j < 4; ++j) acc[i][j] = zz;

    for (int c0 = 0; c0 < CC; c0 += 32) {
        __syncthreads();
        #pragma unroll
        for (int cpy = 0; cpy < 2; ++cpy) {
            int r = w * 32 + cpy * 16 + lrow;
            gld16(Sb + (size_t)r * CC + c0 + lchunk, &Xt[(w * 32 + cpy * 16) * 32]);
        }
        #pragma unroll
        for (int s = 0; s < 3; ++s)
            #pragma unroll
            for (int cpy = 0; cpy < 2; ++cpy) {
                int r = w * 32 + cpy * 16 + lrow;
                gld16(Wb + (size_t)s * CC * CC + (size_t)r * CC + c0 + lchunk,
                      &Wt[s][(w * 32 + cpy * 16) * 32]);
            }
        __syncthreads();

        bf16x8 sf[4];
        #pragma unroll
        for (int i = 0; i < 4; ++i) sf[i] = *(const bf16x8*)&Xt[(wn + i * 16 + l15) * 32 + kb];
        #pragma unroll
        for (int s = 0; s < 3; ++s) {
            bf16x8 wf[4];
            #pragma unroll
            for (int i = 0; i < 4; ++i) wf[i] = *(const bf16x8*)&Wt[s][(wm + i * 16 + l15) * 32 + kb];
            #pragma unroll
            for (int mt = 0; mt < 4; ++mt)
                #pragma unroll
                for (int nt = 0; nt < 4; ++nt)
                    acc[mt][nt] = __builtin_amdgcn_mfma_f32_16x16x32_bf16(wf[mt], sf[nt], acc[mt][nt], 0, 0, 0);
        }
    }

    #pragma unroll
    for (int mt = 0; mt < 4; ++mt) {
        int o0 = wtile * 128 + wm + mt * 16 + (lane >> 4) * 4;
        #pragma unroll
        for (int nt = 0; nt < 4; ++nt) {
            int row = ntile * 128 + wn + nt * 16 + l15;
            int tb = (row >= bnd) ? tb0 + 1 : tb0;
            int n  = row - tb * NN;
            #pragma unroll
            for (int r = 0; r < 4; ++r)
                Y[((size_t)tb * CC + o0 + r) * NN + n] = acc[mt][nt][r] * scale[o0 + r] + shift[o0 + r];
        }
    }
}

extern "C" void kernel_launch(void* const* d_in, const int* in_sizes, int n_in,
                              void* d_out, int out_size, void* d_ws, size_t ws_size,
                              hipStream_t stream) {
    const float* x    = (const float*)d_in[0];
    const float* q_cw = (const float*)d_in[1];
    const float* q_cb = (const float*)d_in[2];
    const float* q_bg = (const float*)d_in[3];
    const float* q_bb = (const float*)d_in[4];
    const float* q_bm = (const float*)d_in[5];
    const float* q_bv = (const float*)d_in[6];
    const float* k_cw = (const float*)d_in[7];
    const float* k_cb = (const float*)d_in[8];
    const float* k_bg = (const float*)d_in[9];
    const float* k_bb = (const float*)d_in[10];
    const float* k_bm = (const float*)d_in[11];
    const float* k_bv = (const float*)d_in[12];
    const float* v_cw = (const float*)d_in[13];
    const float* v_cb = (const float*)d_in[14];
    const float* v_bg = (const float*)d_in[15];
    const float* v_bb = (const float*)d_in[16];
    const float* v_bm = (const float*)d_in[17];
    const float* v_bv = (const float*)d_in[18];
    const float* p_cw = (const float*)d_in[19];
    const float* p_cb = (const float*)d_in[20];
    const float* p_bg = (const float*)d_in[21];
    const float* p_bb = (const float*)d_in[22];
    const float* p_bm = (const float*)d_in[23];
    const float* p_bv = (const float*)d_in[24];
    const float* pshw = (const float*)d_in[25];
    const float* pllw = (const float*)d_in[26];
    const float* ppb  = (const float*)d_in[27];
    float* out = (float*)d_out;

    // ws map (compact layouts, 242 MB budget):
    //   [0,26)    XS head spikes (25.7MB); reused as QS after gemm_qkv
    //   [26,78)   Yq fp32 (51.4MB); [26,52) reused as OS after attn inputs consumed
    //   [78,130)  Yk fp32
    //   [130,182) Yv fp32
    //   [182,208) KS ; [208,234) VS
    //   [234,..)  W3 (6MB) + SS/SH
    if (ws_size < (size_t)242 * 1024 * 1024) return;
    char* W = (char*)d_ws;
    u16*   XS = (u16*)W;
    u16*   QS = (u16*)W;
    float* Yq = (float*)(W + ((size_t)26 << 20));
    float* Yk = (float*)(W + ((size_t)78 << 20));
    float* Yv = (float*)(W + ((size_t)130 << 20));
    u16*   KS = (u16*)(W + ((size_t)182 << 20));
    u16*   VS = (u16*)(W + ((size_t)208 << 20));
    u16*   OS = (u16*)(W + ((size_t)26 << 20));   // overwrites Yq (dead after k_lif_all)
    u16*   W3 = (u16*)(W + ((size_t)234 << 20));
    float* SS = (float*)(W + ((size_t)234 << 20) + 6291456);  // scale[4][512]
    float* SH = SS + 2048;                                     // shift[4][512]

    k_prep_w<<<4096, 256, 0, stream>>>(q_cw, k_cw, v_cw, p_cw, W3);
    k_prep_bn4<<<8, 256, 0, stream>>>(q_cb, q_bg, q_bb, q_bm, q_bv,
                                      k_cb, k_bg, k_bb, k_bm, k_bv,
                                      v_cb, v_bg, v_bb, v_bm, v_bv,
                                      p_cb, p_bg, p_bb, p_bm, p_bv, SS, SH);

    k_head_lif<<<dim3(4, 32, 2), 256, 0, stream>>>(x, XS);

    // merged Q/K/V projection over compact rows; Yq,Yk,Yv at 52MB stride
    k_gemm_qkv<<<dim3(12, 196), 256, 0, stream>>>(XS, W3, SS, SH, Yq);

    // all 5 LIF chains in one launch -> compact bf16 spikes
    const int validBlocks = (int)(CSTRIDE / 256);   // 12544
    k_lif_all<<<validBlocks, 256, 0, stream>>>(Yq, Yk, Yv, QS, KS, VS, pshw, pllw, ppb);

    k_attn<<<TBB * NHH, 256, 0, stream>>>(QS, KS, VS, OS);
    k_attn_lif<<<validBlocks, 256, 0, stream>>>(OS);

    k_gemm_proj<<<dim3(4, 196), 256, 0, stream>>>(OS, W3 + 3 * 786432, SS + 1536, SH + 1536, out);
}

// Round 8
// 411.537 us; speedup vs baseline: 1.2829x; 1.0298x over previous
//
#include <hip/hip_runtime.h>
#include <hip/hip_bf16.h>
#include <math.h>

typedef unsigned short u16;
typedef unsigned int   u32;

#define CC 512
#define NN 196
#define TT 4
#define BB 32
#define TBB 128
#define NHH 8
#define HD 64

// compact-row layout: row = tb*196 + n, M = 128*196 = 25088 rows
#define MROWS   25088
#define ROWS_T  6272                      // rows per t-slice (32*196)
#define CSTRIDE ((size_t)ROWS_T * CC)     // elems per t-slice = 3,211,264

typedef __attribute__((ext_vector_type(8))) short bf16x8;
typedef __attribute__((ext_vector_type(4))) float f32x4;

__device__ __forceinline__ u16 f2bf(float f) {
    __hip_bfloat16 h = __float2bfloat16(f);
    return *(u16*)&h;
}
__device__ __forceinline__ float bf2f(u16 u) {
    u32 ui = ((u32)u) << 16;
    return __uint_as_float(ui);
}
__device__ __forceinline__ u32 pk2(u16 a, u16 b) { return (u32)a | ((u32)b << 16); }

// async 16B/lane global->LDS; lds base must be wave-uniform
__device__ __forceinline__ void gld16(const void* g, void* l) {
    __builtin_amdgcn_global_load_lds(
        (const __attribute__((address_space(1))) void*)g,
        (__attribute__((address_space(3))) void*)l, 16, 0, 0);
}

// ---------------- merged prep: W 3-split (blocks 0..4095) + BN folds (blocks 4096..4103) ----------------
__global__ __launch_bounds__(256) void k_prep(
    const float* __restrict__ qw, const float* __restrict__ kw,
    const float* __restrict__ vw, const float* __restrict__ pw,
    const float* __restrict__ cb0, const float* __restrict__ bg0, const float* __restrict__ bb0,
    const float* __restrict__ bm0, const float* __restrict__ bv0,
    const float* __restrict__ cb1, const float* __restrict__ bg1, const float* __restrict__ bb1,
    const float* __restrict__ bm1, const float* __restrict__ bv1,
    const float* __restrict__ cb2, const float* __restrict__ bg2, const float* __restrict__ bb2,
    const float* __restrict__ bm2, const float* __restrict__ bv2,
    const float* __restrict__ cb3, const float* __restrict__ bg3, const float* __restrict__ bb3,
    const float* __restrict__ bm3, const float* __restrict__ bv3,
    u16* __restrict__ W3, float* __restrict__ SS, float* __restrict__ SH) {
    if (blockIdx.x < 4096) {
        size_t idx = (size_t)blockIdx.x * 256 + threadIdx.x;   // 4 * 262144
        int g = (int)(idx >> 18);
        size_t rem = idx & 262143;
        const float* Ws = (g == 0) ? qw : (g == 1) ? kw : (g == 2) ? vw : pw;
        float w  = Ws[rem];
        u16 u0 = f2bf(w);      float b0 = bf2f(u0);
        float r1 = w - b0;
        u16 u1 = f2bf(r1);     float b1 = bf2f(u1);
        float r2 = r1 - b1;
        u16 u2 = f2bf(r2);
        size_t base = (size_t)g * 786432 + rem;
        W3[base] = u0; W3[base + 262144] = u1; W3[base + 524288] = u2;
        return;
    }
    int idx = (blockIdx.x - 4096) * 256 + threadIdx.x;   // 0..2047
    int g = idx >> 9, o = idx & 511;
    const float* cb = g == 0 ? cb0 : g == 1 ? cb1 : g == 2 ? cb2 : cb3;
    const float* bg = g == 0 ? bg0 : g == 1 ? bg1 : g == 2 ? bg2 : bg3;
    const float* bb = g == 0 ? bb0 : g == 1 ? bb1 : g == 2 ? bb2 : bb3;
    const float* bm = g == 0 ? bm0 : g == 1 ? bm1 : g == 2 ? bm2 : bm3;
    const float* bv = g == 0 ? bv0 : g == 1 ? bv1 : g == 2 ? bv2 : bv3;
    float inv = bg[o] / sqrtf(bv[o] + 1e-5f);
    SS[g * 512 + o] = inv;
    SH[g * 512 + o] = (cb[o] - bm[o]) * inv + bb[o];
}

// ---------------- head LIF + transpose: x[t][b][C][196] -> XS[tb*196+n][C] bf16 spikes (compact) ----------------
// grid (4 n-tiles, 32 b, 8 c-groups of 64)
__global__ __launch_bounds__(256) void k_head_lif(const float* __restrict__ x, u16* __restrict__ XS) {
    __shared__ float T[64][65];
    const int tid = threadIdx.x;
    const int n0 = blockIdx.x * 64;       // 0..3 * 64
    const int b  = blockIdx.y;            // 0..31
    const int c_base = blockIdx.z * 64;   // 0..7 * 64
    const int n_l = tid & 63;
    const int c_r0 = tid >> 6;            // 0..3
    const int n_r = tid >> 2;             // 0..63
    const int cq  = (tid & 3) * 16;
    const bool wv = (n0 + n_r) < NN;

    float v[16];
    #pragma unroll
    for (int j = 0; j < 16; ++j) v[j] = 0.f;
    for (int t = 0; t < TT; ++t) {
        const size_t xb = ((size_t)(t * BB + b) * CC + c_base) * NN;
        float s[16];
        #pragma unroll
        for (int j = 0; j < 16; ++j) {
            int c_l = c_r0 + 4 * j;
            float xv = (n0 + n_l < NN) ? x[xb + (size_t)c_l * NN + n0 + n_l] : 0.f;
            float h = v[j] + (xv - v[j]) * 0.5f;
            s[j] = (h >= 1.f) ? 1.f : 0.f;
            v[j] = (h >= 1.f) ? 0.f : h;
        }
        __syncthreads();
        #pragma unroll
        for (int j = 0; j < 16; ++j) T[c_r0 + 4 * j][n_l] = s[j];
        __syncthreads();
        if (wv) {
            const size_t ob = ((size_t)(t * BB + b) * NN + n0 + n_r) * CC + c_base + cq;
            u16 u[16];
            #pragma unroll
            for (int m = 0; m < 16; ++m) u[m] = (T[cq + m][n_r] != 0.f) ? 0x3F80 : 0;
            uint4 q0 = make_uint4(pk2(u[0],u[1]),  pk2(u[2],u[3]),  pk2(u[4],u[5]),  pk2(u[6],u[7]));
            uint4 q1 = make_uint4(pk2(u[8],u[9]),  pk2(u[10],u[11]),pk2(u[12],u[13]),pk2(u[14],u[15]));
            *(uint4*)(XS + ob)     = q0;
            *(uint4*)(XS + ob + 8) = q1;
        }
        __syncthreads();
    }
}

// ---------------- merged QKV MFMA GEMM over compact rows, 3-split bf16 weights ----------------
// 1D grid 2352 with XCD-aware swizzle: xcd = bid&7 gets slab work = xcd*294 + bid/8;
// decode ntile = work/12, gw = work%12 -> all 12 sharers of a spike tile on one XCD.
#define YSTRIDE_F 13631488   // 52MB / 4
__global__ __launch_bounds__(256) void k_gemm_qkv(const u16* __restrict__ S, const u16* __restrict__ W3,
                                                  const float* __restrict__ scale, const float* __restrict__ shift,
                                                  float* __restrict__ Y) {
    __shared__ __align__(16) u16 Xt[128 * 32];
    __shared__ __align__(16) u16 Wt[3][128 * 32];
    const int tid  = threadIdx.x;
    const int lane = tid & 63;
    const int w    = tid >> 6;
    const int bid  = blockIdx.x;
    const int work = (bid & 7) * 294 + (bid >> 3);
    const int ntile = work / 12;          // 0..195
    const int gw    = work - ntile * 12;
    const int g     = gw >> 2;
    const int wtile = gw & 3;
    const u16* Sb = S + (size_t)ntile * 128 * CC;
    const u16* Wb = W3 + (size_t)g * 786432 + (size_t)(wtile * 128) * CC;
    const float* scl = scale + g * 512;
    const float* shf = shift + g * 512;
    float* Yg = Y + (size_t)g * YSTRIDE_F;

    const int lrow   = lane >> 2;        // 0..15
    const int lchunk = (lane & 3) * 8;   // bf16 elems
    const int l15 = lane & 15;
    const int kb  = (lane >> 4) * 8;
    const int wm = (w >> 1) * 64, wn = (w & 1) * 64;

    f32x4 acc[4][4];
    f32x4 zz = {0.f, 0.f, 0.f, 0.f};
    #pragma unroll
    for (int i = 0; i < 4; ++i)
        #pragma unroll
        for (int j = 0; j < 4; ++j) acc[i][j] = zz;

    for (int c0 = 0; c0 < CC; c0 += 32) {
        __syncthreads();
        #pragma unroll
        for (int cpy = 0; cpy < 2; ++cpy) {
            int r = w * 32 + cpy * 16 + lrow;
            gld16(Sb + (size_t)r * CC + c0 + lchunk, &Xt[(w * 32 + cpy * 16) * 32]);
        }
        #pragma unroll
        for (int s = 0; s < 3; ++s)
            #pragma unroll
            for (int cpy = 0; cpy < 2; ++cpy) {
                int r = w * 32 + cpy * 16 + lrow;
                gld16(Wb + (size_t)s * CC * CC + (size_t)r * CC + c0 + lchunk,
                      &Wt[s][(w * 32 + cpy * 16) * 32]);
            }
        __syncthreads();

        bf16x8 sf[4];
        #pragma unroll
        for (int i = 0; i < 4; ++i) sf[i] = *(const bf16x8*)&Xt[(wm + i * 16 + l15) * 32 + kb];
        #pragma unroll
        for (int s = 0; s < 3; ++s) {
            bf16x8 wf[4];
            #pragma unroll
            for (int i = 0; i < 4; ++i) wf[i] = *(const bf16x8*)&Wt[s][(wn + i * 16 + l15) * 32 + kb];
            #pragma unroll
            for (int mt = 0; mt < 4; ++mt)
                #pragma unroll
                for (int nt = 0; nt < 4; ++nt)
                    acc[mt][nt] = __builtin_amdgcn_mfma_f32_16x16x32_bf16(sf[mt], wf[nt], acc[mt][nt], 0, 0, 0);
        }
    }

    // epilogue: C/D layout col = lane&15, row = (lane>>4)*4 + reg
    #pragma unroll
    for (int nt = 0; nt < 4; ++nt) {
        int o = wtile * 128 + wn + nt * 16 + l15;
        float sc = scl[o], sh = shf[o];
        #pragma unroll
        for (int mt = 0; mt < 4; ++mt) {
            int r0 = ntile * 128 + wm + mt * 16 + (lane >> 4) * 4;
            #pragma unroll
            for (int r = 0; r < 4; ++r)
                Yg[(size_t)(r0 + r) * CC + o] = acc[mt][nt][r] * sc + sh;
        }
    }
}

// ---------------- merged LIF: q (3 chains) + k + v -> compact bf16 spikes ----------------
__global__ __launch_bounds__(256) void k_lif_all(const float* __restrict__ Yq, const float* __restrict__ Yk,
                                                 const float* __restrict__ Yv, u16* __restrict__ QS,
                                                 u16* __restrict__ KS, u16* __restrict__ VS,
                                                 const float* __restrict__ pw_,
                                                 const float* __restrict__ pl_,
                                                 const float* __restrict__ pb_) {
    size_t idx = (size_t)blockIdx.x * 256 + threadIdx.x;   // flat over one t-slice (3,211,264)
    float pw = log1pf(expf(pw_[0]));
    float pl = log1pf(expf(pl_[0]));
    float pb = pb_[0];
    float von = 0.f, voff = 0.f, vpp = 0.f, vk = 0.f, vv = 0.f;
    #pragma unroll
    for (int t = 0; t < TT; ++t) {
        size_t off = idx + (size_t)t * CSTRIDE;
        float qv = Yq[off], kv = Yk[off], xv = Yv[off];
        float h;
        h = von  + ( qv - von ) * 0.5f; bool s1 = (h >= 1.f); von  = s1 ? 0.f : h;
        h = voff + (-qv - voff) * 0.5f; bool s2 = (h >= 1.f); voff = s2 ? 0.f : h;
        float diff = pw * (s1 ? 1.f : 0.f) - pl * (s2 ? 1.f : 0.f) + pb;
        h = vpp  + (diff - vpp) * 0.5f; bool sp = (h >= 1.f); vpp  = sp ? 0.f : h;
        h = vk   + ( kv - vk  ) * 0.5f; bool sk = (h >= 1.f); vk   = sk ? 0.f : h;
        h = vv   + ( xv - vv  ) * 0.5f; bool sv = (h >= 1.f); vv   = sv ? 0.f : h;
        QS[off] = sp ? 0x3F80 : 0;
        KS[off] = sk ? 0x3F80 : 0;
        VS[off] = sv ? 0x3F80 : 0;
    }
}

// ---------------- MFMA attention per (tb,h): kv = K^T V ; O = 0.125 * Q_pp kv -> bf16 compact ----------------
__global__ __launch_bounds__(256) void k_attn(const u16* __restrict__ Q, const u16* __restrict__ K,
                                              const u16* __restrict__ V, u16* __restrict__ OS) {
    __shared__ __align__(16) u16 sm[19584];   // max(2*64*136, 208*72 + 64*72) u16 = 39168 B
    u16* Kt  = sm;            // phase A: [64 d][136]
    u16* Vt  = sm + 8704;     // phase A: [64 e][136]
    u16* Qs  = sm;            // phase B: [208 n][72]
    u16* kvT = sm + 14976;    // phase B: [64 e][72]

    const int tid = threadIdx.x;
    const int tb  = blockIdx.x >> 3;
    const int h   = blockIdx.x & 7;
    const size_t gb = (size_t)tb * NN * CC + (size_t)h * HD;

    const int srow = tid >> 2;            // 0..63 staging row
    const int sdq  = (tid & 3) * 16;      // 0,16,32,48

    const int lane = tid & 63;
    const int w    = tid >> 6;
    const int l15  = lane & 15;
    const int kb8  = (lane >> 4) * 8;
    const int quad = (lane >> 4) * 4;
    const int dh = (w >> 1) * 32, eh = (w & 1) * 32;

    f32x4 accA[2][2];
    f32x4 zz = {0.f, 0.f, 0.f, 0.f};
    #pragma unroll
    for (int i = 0; i < 2; ++i)
        #pragma unroll
        for (int j = 0; j < 2; ++j) accA[i][j] = zz;

    const uint4 z4 = make_uint4(0, 0, 0, 0);

    // ---- phase A over 2 n-chunks of 128
    #pragma unroll
    for (int ch = 0; ch < 2; ++ch) {
        if (ch) __syncthreads();
        #pragma unroll
        for (int c = 0; c < 2; ++c) {
            int n  = ch * 128 + c * 64 + srow;
            int nl = c * 64 + srow;
            bool valid = n < NN;
            const u16* kr = K + gb + (size_t)n * CC + sdq;
            const u16* vr = V + gb + (size_t)n * CC + sdq;
            uint4 ka  = valid ? *(const uint4*)kr : z4;
            uint4 kb2 = valid ? *(const uint4*)(kr + 8) : z4;
            uint4 va  = valid ? *(const uint4*)vr : z4;
            uint4 vb2 = valid ? *(const uint4*)(vr + 8) : z4;
            u32 kwv[8] = {ka.x, ka.y, ka.z, ka.w, kb2.x, kb2.y, kb2.z, kb2.w};
            u32 vwv[8] = {va.x, va.y, va.z, va.w, vb2.x, vb2.y, vb2.z, vb2.w};
            #pragma unroll
            for (int i = 0; i < 8; ++i) {
                Kt[(sdq + 2 * i) * 136 + nl]     = (u16)(kwv[i] & 0xFFFF);
                Kt[(sdq + 2 * i + 1) * 136 + nl] = (u16)(kwv[i] >> 16);
                Vt[(sdq + 2 * i) * 136 + nl]     = (u16)(vwv[i] & 0xFFFF);
                Vt[(sdq + 2 * i + 1) * 136 + nl] = (u16)(vwv[i] >> 16);
            }
        }
        __syncthreads();
        #pragma unroll
        for (int k0 = 0; k0 < 128; k0 += 32) {
            bf16x8 af[2], bv[2];
            #pragma unroll
            for (int i = 0; i < 2; ++i) {
                af[i] = *(const bf16x8*)&Kt[(dh + i * 16 + l15) * 136 + k0 + kb8];
                bv[i] = *(const bf16x8*)&Vt[(eh + i * 16 + l15) * 136 + k0 + kb8];
            }
            #pragma unroll
            for (int i = 0; i < 2; ++i)
                #pragma unroll
                for (int j = 0; j < 2; ++j)
                    accA[i][j] = __builtin_amdgcn_mfma_f32_16x16x32_bf16(af[i], bv[j], accA[i][j], 0, 0, 0);
        }
    }
    __syncthreads();   // all waves done with Kt/Vt before overwrite

    // ---- write kv^T (bf16, exact: integers <= 196) and stage Q
    #pragma unroll
    for (int i = 0; i < 2; ++i)
        #pragma unroll
        for (int j = 0; j < 2; ++j)
            #pragma unroll
            for (int r = 0; r < 4; ++r) {
                int e = eh + j * 16 + l15;
                int d = dh + i * 16 + quad + r;
                kvT[e * 72 + d] = f2bf(accA[i][j][r]);
            }
    #pragma unroll
    for (int p = 0; p < 4; ++p) {
        int n = p * 64 + srow;
        if (n < 208) {
            if (n < NN) {
                const u16* qr = Q + gb + (size_t)n * CC + sdq;
                uint4 qa  = *(const uint4*)qr;
                uint4 qb2 = *(const uint4*)(qr + 8);
                u32 qwv[8] = {qa.x, qa.y, qa.z, qa.w, qb2.x, qb2.y, qb2.z, qb2.w};
                #pragma unroll
                for (int i = 0; i < 8; ++i) {
                    Qs[n * 72 + sdq + 2 * i]     = (u16)(qwv[i] & 0xFFFF);
                    Qs[n * 72 + sdq + 2 * i + 1] = (u16)(qwv[i] >> 16);
                }
            } else {
                #pragma unroll
                for (int i = 0; i < 16; ++i) Qs[n * 72 + sdq + i] = 0;
            }
        }
    }
    __syncthreads();

    // ---- phase B: wave w owns e-tile [w*16, w*16+16)
    bf16x8 bq0 = *(const bf16x8*)&kvT[(w * 16 + l15) * 72 + 0  + kb8];
    bf16x8 bq1 = *(const bf16x8*)&kvT[(w * 16 + l15) * 72 + 32 + kb8];
    u16* ob = OS + (size_t)tb * NN * CC + (size_t)h * HD + w * 16 + l15;
    #pragma unroll
    for (int nt = 0; nt < 13; ++nt) {
        f32x4 acc = zz;
        bf16x8 a0 = *(const bf16x8*)&Qs[(nt * 16 + l15) * 72 + 0  + kb8];
        bf16x8 a1 = *(const bf16x8*)&Qs[(nt * 16 + l15) * 72 + 32 + kb8];
        acc = __builtin_amdgcn_mfma_f32_16x16x32_bf16(a0, bq0, acc, 0, 0, 0);
        acc = __builtin_amdgcn_mfma_f32_16x16x32_bf16(a1, bq1, acc, 0, 0, 0);
        #pragma unroll
        for (int r = 0; r < 4; ++r) {
            int n = nt * 16 + quad + r;
            if (n < NN) ob[(size_t)n * CC] = f2bf(acc[r] * 0.125f);
        }
    }
}

// ---------------- attn LIF (vth=0.5), compact flat, in place on bf16 ----------------
__global__ __launch_bounds__(256) void k_attn_lif(u16* __restrict__ OS) {
    size_t idx = (size_t)blockIdx.x * 256 + threadIdx.x;   // flat over one t-slice
    float v = 0.f;
    #pragma unroll
    for (int t = 0; t < TT; ++t) {
        size_t off = idx + (size_t)t * CSTRIDE;
        float xv = bf2f(OS[off]);
        float h = v + (xv - v) * 0.5f;
        bool s = (h >= 0.5f);
        v = s ? 0.f : h;
        OS[off] = s ? 0x3F80 : 0;
    }
}

// ---------------- final projection GEMM: out[tb][o][n] = BN(W_p x spikes^T), compact rows ----------------
// 1D grid 784 with XCD-aware swizzle (98 work items per XCD slab).
__global__ __launch_bounds__(256) void k_gemm_proj(const u16* __restrict__ S, const u16* __restrict__ W3,
                                                   const float* __restrict__ scale, const float* __restrict__ shift,
                                                   float* __restrict__ Y) {
    __shared__ __align__(16) u16 Xt[128 * 32];
    __shared__ __align__(16) u16 Wt[3][128 * 32];
    const int tid  = threadIdx.x;
    const int lane = tid & 63;
    const int w    = tid >> 6;
    const int bid  = blockIdx.x;
    const int work = (bid & 7) * 98 + (bid >> 3);
    const int ntile = work >> 2;    // 0..195
    const int wtile = work & 3;     // 0..3
    const u16* Sb = S + (size_t)ntile * 128 * CC;
    const u16* Wb = W3 + (size_t)(wtile * 128) * CC;

    const int lrow   = lane >> 2;
    const int lchunk = (lane & 3) * 8;
    const int l15 = lane & 15;
    const int kb  = (lane >> 4) * 8;
    const int wm = (w >> 1) * 64, wn = (w & 1) * 64;

    // a 128-row tile crosses at most one tb boundary
    const int tb0 = (ntile * 128) / NN;
    const int bnd = (tb0 + 1) * NN;

    f32x4 acc[4][4];
    f32x4 zz = {0.f, 0.f, 0.f, 0.f};
    #pragma unroll
    for (int i = 0; i < 4; ++i)
        #pragma unroll
        for (int j = 0; j < 4; ++j) acc[i][j] = zz;

    for (int c0 = 0; c0 < CC; c0 += 32) {
        __syncthreads();
        #pragma unroll
        for (int cpy = 0; cpy < 2; ++cpy) {
            int r = w * 32 + cpy * 16 + lrow;
            gld16(Sb + (size_t)r * CC + c0 + lchunk, &Xt[(w * 32 + cpy * 16) * 32]);
        }
        #pragma unroll
        for (int s = 0; s < 3; ++s)
            #pragma unroll
            for (int cpy = 0; cpy < 2; ++cpy) {
                int r = w * 32 + cpy * 16 + lrow;
                gld16(Wb + (size_t)s * CC * CC + (size_t)r * CC + c0 + lchunk,
                      &Wt[s][(w * 32 + cpy * 16) * 32]);
            }
        __syncthreads();

        bf16x8 sf[4];
        #pragma unroll
        for (int i = 0; i < 4; ++i) sf[i] = *(const bf16x8*)&Xt[(wn + i * 16 + l15) * 32 + kb];
        #pragma unroll
        for (int s = 0; s < 3; ++s) {
            bf16x8 wf[4];
            #pragma unroll
            for (int i = 0; i < 4; ++i) wf[i] = *(const bf16x8*)&Wt[s][(wm + i * 16 + l15) * 32 + kb];
            #pragma unroll
            for (int mt = 0; mt < 4; ++mt)
                #pragma unroll
                for (int nt = 0; nt < 4; ++nt)
                    acc[mt][nt] = __builtin_amdgcn_mfma_f32_16x16x32_bf16(wf[mt], sf[nt], acc[mt][nt], 0, 0, 0);
        }
    }

    #pragma unroll
    for (int mt = 0; mt < 4; ++mt) {
        int o0 = wtile * 128 + wm + mt * 16 + (lane >> 4) * 4;
        #pragma unroll
        for (int nt = 0; nt < 4; ++nt) {
            int row = ntile * 128 + wn + nt * 16 + l15;
            int tb = (row >= bnd) ? tb0 + 1 : tb0;
            int n  = row - tb * NN;
            #pragma unroll
            for (int r = 0; r < 4; ++r)
                Y[((size_t)tb * CC + o0 + r) * NN + n] = acc[mt][nt][r] * scale[o0 + r] + shift[o0 + r];
        }
    }
}

extern "C" void kernel_launch(void* const* d_in, const int* in_sizes, int n_in,
                              void* d_out, int out_size, void* d_ws, size_t ws_size,
                              hipStream_t stream) {
    const float* x    = (const float*)d_in[0];
    const float* q_cw = (const float*)d_in[1];
    const float* q_cb = (const float*)d_in[2];
    const float* q_bg = (const float*)d_in[3];
    const float* q_bb = (const float*)d_in[4];
    const float* q_bm = (const float*)d_in[5];
    const float* q_bv = (const float*)d_in[6];
    const float* k_cw = (const float*)d_in[7];
    const float* k_cb = (const float*)d_in[8];
    const float* k_bg = (const float*)d_in[9];
    const float* k_bb = (const float*)d_in[10];
    const float* k_bm = (const float*)d_in[11];
    const float* k_bv = (const float*)d_in[12];
    const float* v_cw = (const float*)d_in[13];
    const float* v_cb = (const float*)d_in[14];
    const float* v_bg = (const float*)d_in[15];
    const float* v_bb = (const float*)d_in[16];
    const float* v_bm = (const float*)d_in[17];
    const float* v_bv = (const float*)d_in[18];
    const float* p_cw = (const float*)d_in[19];
    const float* p_cb = (const float*)d_in[20];
    const float* p_bg = (const float*)d_in[21];
    const float* p_bb = (const float*)d_in[22];
    const float* p_bm = (const float*)d_in[23];
    const float* p_bv = (const float*)d_in[24];
    const float* pshw = (const float*)d_in[25];
    const float* pllw = (const float*)d_in[26];
    const float* ppb  = (const float*)d_in[27];
    float* out = (float*)d_out;

    // ws map (compact layouts, 242 MB budget):
    //   [0,26)    XS head spikes (25.7MB); reused as QS after gemm_qkv
    //   [26,78)   Yq fp32 (51.4MB); [26,52) reused as OS after attn inputs consumed
    //   [78,130)  Yk fp32
    //   [130,182) Yv fp32
    //   [182,208) KS ; [208,234) VS
    //   [234,..)  W3 (6MB) + SS/SH
    if (ws_size < (size_t)242 * 1024 * 1024) return;
    char* W = (char*)d_ws;
    u16*   XS = (u16*)W;
    u16*   QS = (u16*)W;
    float* Yq = (float*)(W + ((size_t)26 << 20));
    float* Yk = (float*)(W + ((size_t)78 << 20));
    float* Yv = (float*)(W + ((size_t)130 << 20));
    u16*   KS = (u16*)(W + ((size_t)182 << 20));
    u16*   VS = (u16*)(W + ((size_t)208 << 20));
    u16*   OS = (u16*)(W + ((size_t)26 << 20));   // overwrites Yq (dead after k_lif_all)
    u16*   W3 = (u16*)(W + ((size_t)234 << 20));
    float* SS = (float*)(W + ((size_t)234 << 20) + 6291456);  // scale[4][512]
    float* SH = SS + 2048;                                     // shift[4][512]

    k_prep<<<4104, 256, 0, stream>>>(q_cw, k_cw, v_cw, p_cw,
                                     q_cb, q_bg, q_bb, q_bm, q_bv,
                                     k_cb, k_bg, k_bb, k_bm, k_bv,
                                     v_cb, v_bg, v_bb, v_bm, v_bv,
                                     p_cb, p_bg, p_bb, p_bm, p_bv, W3, SS, SH);

    k_head_lif<<<dim3(4, 32, 8), 256, 0, stream>>>(x, XS);

    // merged Q/K/V projection, XCD-swizzled 1D grid; Yq,Yk,Yv at 52MB stride
    k_gemm_qkv<<<2352, 256, 0, stream>>>(XS, W3, SS, SH, Yq);

    // all 5 LIF chains in one launch -> compact bf16 spikes
    const int validBlocks = (int)(CSTRIDE / 256);   // 12544
    k_lif_all<<<validBlocks, 256, 0, stream>>>(Yq, Yk, Yv, QS, KS, VS, pshw, pllw, ppb);

    k_attn<<<TBB * NHH, 256, 0, stream>>>(QS, KS, VS, OS);
    k_attn_lif<<<validBlocks, 256, 0, stream>>>(OS);

    k_gemm_proj<<<784, 256, 0, stream>>>(OS, W3 + 3 * 786432, SS + 1536, SH + 1536, out);
}